// Round 16
// baseline (981.429 us; speedup 1.0000x reference)
//
#include <hip/hip_runtime.h>
#include <hip/hip_bf16.h>
#include <math.h>

#define TT 64
#define NN 2000
#define FIN 32
#define HH 64
#define CC 10
#define EE 32000
#define ETOT 34000   // E + N self loops
#define THL 4096     // T*H
#define EPSBN 1e-5f

// ---------------- workspace layout (float offsets) ----------------
#define OFF_WC   0u          // WCh bf16 [2048][2048]
#define OFF_XA   4000000u    // 8,192,000  [N,T,H] fp32
#define OFF_XB   12192000u   // 8,192,000  (x_agg bf16 C; then xw scratch)
#define OFF_XC   20384000u   // 8,192,000  (first: XAh_t bf16 [4096][2048]; then fusion out fp32)
#define OFF_DEG  28576000u   // 2048
#define OFF_H1   28578048u   // 128,000 (unused)
#define OFF_CNT  28706048u   // int 2048
#define OFF_CUR  28708096u   // int 2048
#define OFF_OFF  28710144u   // int 2064
#define OFF_CSRS 28712208u   // int 34016
#define OFF_CSRN 28746224u   // float 34016
#define OFF_HST  28780240u   // float 128,000  (GRU h-state)

typedef __attribute__((ext_vector_type(8))) short short8v;
typedef __attribute__((ext_vector_type(4))) float f32x4;

__device__ __forceinline__ float fsigmoid(float x) { return 1.f / (1.f + __expf(-x)); }
__device__ __forceinline__ unsigned short f2bf(float f) {
    __hip_bfloat16 h = __float2bfloat16(f);
    return *reinterpret_cast<unsigned short*>(&h);
}
__device__ __forceinline__ float bf2f(unsigned short u) {
    unsigned int x = ((unsigned int)u) << 16;
    return __int_as_float(x);
}
__device__ __forceinline__ float rdlane(float v, int k) {
    return __int_as_float(__builtin_amdgcn_readlane(__float_as_int(v), k));
}

// ---------------- CSR build ----------------
__global__ void k_zero(int* cnt, int* cur, float* deg) {
    int i = blockIdx.x * 256 + threadIdx.x;
    if (i < 2048) { cnt[i] = 0; cur[i] = 0; deg[i] = 0.f; }
}

__global__ void k_count(const int* __restrict__ ei, const float* __restrict__ ew,
                        int* cnt, float* deg) {
    int e = blockIdx.x * 256 + threadIdx.x;
    if (e < ETOT) {
        int dst; float w;
        if (e < EE) { dst = ei[EE + e]; w = ew[e]; }
        else        { dst = e - EE;     w = 1.f; }
        atomicAdd(&cnt[dst], 1);
        atomicAdd(&deg[dst], w);
    }
}

__global__ __launch_bounds__(1024) void k_scan(const int* __restrict__ cnt, int* off) {
    __shared__ int s[2048];
    int tid = threadIdx.x;
    s[tid]        = (tid        < NN) ? cnt[tid]        : 0;
    s[tid + 1024] = (tid + 1024 < NN) ? cnt[tid + 1024] : 0;
    __syncthreads();
    for (int d = 1; d < 2048; d <<= 1) {
        int idx = (tid + 1) * (d << 1) - 1;
        if (idx < 2048) s[idx] += s[idx - d];
        __syncthreads();
    }
    if (tid == 0) s[2047] = 0;
    __syncthreads();
    for (int d = 1024; d >= 1; d >>= 1) {
        int idx = (tid + 1) * (d << 1) - 1;
        if (idx < 2048) { int t = s[idx - d]; s[idx - d] = s[idx]; s[idx] += t; }
        __syncthreads();
    }
    off[tid] = s[tid];
    off[tid + 1024] = s[tid + 1024];
}

__global__ void k_fill(const int* __restrict__ ei, const float* __restrict__ ew,
                       const float* __restrict__ deg, const int* __restrict__ off,
                       int* cur, int* csr_src, float* csr_nrm) {
    int e = blockIdx.x * 256 + threadIdx.x;
    if (e < ETOT) {
        int src, dst; float w;
        if (e < EE) { src = ei[e]; dst = ei[EE + e]; w = ew[e]; }
        else        { src = dst = e - EE;            w = 1.f; }
        float ds = rsqrtf(fmaxf(deg[src], 1e-12f));
        float dd = rsqrtf(fmaxf(deg[dst], 1e-12f));
        int pos = off[dst] + atomicAdd(&cur[dst], 1);
        csr_src[pos] = src;
        csr_nrm[pos] = ds * w * dd;
    }
}

// ---------------- softmax over causal_weight rows -> bf16 WCh [2048 stride] ----------------
__global__ __launch_bounds__(256) void k_softmax(const float* __restrict__ CW,
                                                 unsigned short* __restrict__ WCH) {
    __shared__ float row[NN];
    __shared__ float red[256];
    int r = blockIdx.x, tid = threadIdx.x;
    const float* in = CW + (size_t)r * NN;
    float mx = -1e30f;
    for (int i = tid; i < NN; i += 256) { float v = in[i]; row[i] = v; mx = fmaxf(mx, v); }
    red[tid] = mx; __syncthreads();
    for (int s = 128; s > 0; s >>= 1) {
        if (tid < s) red[tid] = fmaxf(red[tid], red[tid + s]);
        __syncthreads();
    }
    mx = red[0]; __syncthreads();
    float sm = 0.f;
    for (int i = tid; i < NN; i += 256) { float e = __expf(row[i] - mx); row[i] = e; sm += e; }
    red[tid] = sm; __syncthreads();
    for (int s = 128; s > 0; s >>= 1) {
        if (tid < s) red[tid] += red[tid + s];
        __syncthreads();
    }
    float inv = 1.f / red[0];
    unsigned short* out = WCH + (size_t)r * 2048;
    for (int i = tid; i < 2048; i += 256)
        out[i] = (i < NN) ? f2bf(row[i] * inv) : (unsigned short)0;
}

// ---------------- lin_in as tiled GEMM: rows=(n,t), K=32, 64 cols ----------------
__global__ __launch_bounds__(256) void k_lin2(const float* __restrict__ XS,
                                              const float* __restrict__ W,
                                              const float* __restrict__ b,
                                              float* __restrict__ OUT) {
    __shared__ float Wt[FIN][68];   // [k][o]
    __shared__ float As[FIN][68];   // [k][row]
    int tid = threadIdx.x;
    int n = blockIdx.x;
    for (int i = tid; i < HH * FIN; i += 256) { int o = i >> 5, k = i & 31; Wt[k][o] = W[i]; }
    int row = tid >> 2, kq = tid & 3;   // row = t
    {
        const float4* src = (const float4*)(XS + ((size_t)row * NN + n) * FIN + kq * 8);
        float4 v0 = src[0], v1 = src[1];
        As[kq * 8 + 0][row] = v0.x; As[kq * 8 + 1][row] = v0.y;
        As[kq * 8 + 2][row] = v0.z; As[kq * 8 + 3][row] = v0.w;
        As[kq * 8 + 4][row] = v1.x; As[kq * 8 + 5][row] = v1.y;
        As[kq * 8 + 6][row] = v1.z; As[kq * 8 + 7][row] = v1.w;
    }
    __syncthreads();
    int tx = tid & 15, ty = tid >> 4;
    float acc[4][4] = {};
#pragma unroll
    for (int k = 0; k < FIN; ++k) {
        float4 av = *(const float4*)&As[k][ty * 4];
        float4 wv = *(const float4*)&Wt[k][tx * 4];
        acc[0][0] += av.x * wv.x; acc[0][1] += av.x * wv.y; acc[0][2] += av.x * wv.z; acc[0][3] += av.x * wv.w;
        acc[1][0] += av.y * wv.x; acc[1][1] += av.y * wv.y; acc[1][2] += av.y * wv.z; acc[1][3] += av.y * wv.w;
        acc[2][0] += av.z * wv.x; acc[2][1] += av.z * wv.y; acc[2][2] += av.z * wv.z; acc[2][3] += av.z * wv.w;
        acc[3][0] += av.w * wv.x; acc[3][1] += av.w * wv.y; acc[3][2] += av.w * wv.z; acc[3][3] += av.w * wv.w;
    }
    float4 bv = *(const float4*)(b + tx * 4);
#pragma unroll
    for (int ii = 0; ii < 4; ++ii) {
        float4 o;
        o.x = fmaxf(acc[ii][0] + bv.x, 0.f);
        o.y = fmaxf(acc[ii][1] + bv.y, 0.f);
        o.z = fmaxf(acc[ii][2] + bv.z, 0.f);
        o.w = fmaxf(acc[ii][3] + bv.w, 0.f);
        *(float4*)(OUT + ((size_t)n * TT + ty * 4 + ii) * HH + tx * 4) = o;
    }
}

// ---------------- transpose + bf16 cast ----------------
__global__ __launch_bounds__(256) void k_tr(const float* __restrict__ X,
                                            unsigned short* __restrict__ XT) {
    __shared__ unsigned short tile[64][65];
    int cb = blockIdx.x * 64;
    int kb = blockIdx.y * 64;
    int tid = threadIdx.x;
    int r = tid >> 2, cq = tid & 3;
    const float4* src = (const float4*)(X + (size_t)(kb + r) * THL + cb + cq * 16);
#pragma unroll
    for (int j = 0; j < 4; ++j) {
        float4 v = src[j];
        tile[cq * 16 + j * 4 + 0][r] = f2bf(v.x);
        tile[cq * 16 + j * 4 + 1][r] = f2bf(v.y);
        tile[cq * 16 + j * 4 + 2][r] = f2bf(v.z);
        tile[cq * 16 + j * 4 + 3][r] = f2bf(v.w);
    }
    __syncthreads();
    int cl = tid >> 2, kq = tid & 3;
    unsigned short tmp[16];
#pragma unroll
    for (int j = 0; j < 16; ++j) tmp[j] = tile[cl][kq * 16 + j];
    unsigned short* dst = XT + (size_t)(cb + cl) * 2048 + kb + kq * 16;
    *(uint4*)dst = *(uint4*)tmp;
    *(uint4*)(dst + 8) = *(uint4*)(tmp + 8);
}

// ---------------- bf16 MFMA GEMM: C(bf16)[2000,4096] = WCh @ X (via XAh_t) — FROZEN ----------------
__global__ __launch_bounds__(256, 1) void k_gemm_bf(const unsigned short* __restrict__ A,
                                                    const unsigned short* __restrict__ B,
                                                    unsigned short* __restrict__ CH) {
    __shared__ unsigned short As[128][72];
    __shared__ unsigned short Bs[128][72];
    int tid = threadIdx.x;
    int mb = blockIdx.y * 128, nb = blockIdx.x * 128;
    int w = tid >> 6, lane = tid & 63;
    int wr = w >> 1, wc = w & 1;
    int l15 = lane & 15, l4 = lane >> 4;
    f32x4 acc[4][4] = {};
    int arow = tid >> 3, acol = tid & 7;
    const uint4* ga = (const uint4*)(A + (size_t)(mb + arow) * 2048 + acol * 8);
    const uint4* gb = (const uint4*)(B + (size_t)(nb + arow) * 2048 + acol * 8);
    uint4 va[4], vb[4];
#pragma unroll
    for (int i = 0; i < 4; ++i) { va[i] = ga[(size_t)i * 8192]; vb[i] = gb[(size_t)i * 8192]; }
    ga += 8; gb += 8;
    for (int kt = 0; kt < 32; ++kt) {
        __syncthreads();
#pragma unroll
        for (int i = 0; i < 4; ++i) {
            *(uint4*)&As[arow + i * 32][acol * 8] = va[i];
            *(uint4*)&Bs[arow + i * 32][acol * 8] = vb[i];
        }
        __syncthreads();
        if (kt < 31) {
#pragma unroll
            for (int i = 0; i < 4; ++i) { va[i] = ga[(size_t)i * 8192]; vb[i] = gb[(size_t)i * 8192]; }
            ga += 8; gb += 8;
        }
#pragma unroll
        for (int kk = 0; kk < 2; ++kk) {
            short8v af[4], bfr[4];
#pragma unroll
            for (int f = 0; f < 4; ++f) {
                af[f]  = *(const short8v*)&As[wr * 64 + f * 16 + l15][kk * 32 + l4 * 8];
                bfr[f] = *(const short8v*)&Bs[wc * 64 + f * 16 + l15][kk * 32 + l4 * 8];
            }
#pragma unroll
            for (int fm = 0; fm < 4; ++fm)
#pragma unroll
                for (int fn = 0; fn < 4; ++fn)
                    acc[fm][fn] = __builtin_amdgcn_mfma_f32_16x16x32_bf16(af[fm], bfr[fn], acc[fm][fn], 0, 0, 0);
        }
    }
    unsigned short* epi = (unsigned short*)(&As[0][0]) + (size_t)w * (16 * 72);
    int erow8 = lane >> 3;
    int ecol8 = lane & 7;
#pragma unroll
    for (int fm = 0; fm < 4; ++fm) {
        __syncthreads();
#pragma unroll
        for (int fn = 0; fn < 4; ++fn)
#pragma unroll
            for (int rr = 0; rr < 4; ++rr)
                epi[(l4 * 4 + rr) * 72 + fn * 16 + l15] = f2bf(acc[fm][fn][rr]);
        __syncthreads();
#pragma unroll
        for (int rh = 0; rh < 2; ++rh) {
            int lrow = rh * 8 + erow8;
            int grow = mb + wr * 64 + fm * 16 + lrow;
            if (grow < NN) {
                *(uint4*)(CH + (size_t)grow * THL + nb + wc * 64 + ecol8 * 8)
                    = *(const uint4*)&epi[lrow * 72 + ecol8 * 8];
            }
        }
    }
}

// ---------------- fusion as tiled GEMM: K=128 (X fp32 + XAgg bf16), 64 cols ----------------
__global__ __launch_bounds__(256) void k_fus2(const float* __restrict__ X,
                                              const unsigned short* __restrict__ XAH,
                                              const float* __restrict__ W,
                                              const float* __restrict__ b,
                                              float* __restrict__ OUT) {
    __shared__ float Wt[2 * HH][68];
    __shared__ float As[HH][68];
    int tid = threadIdx.x;
    size_t r0 = (size_t)blockIdx.x * 64;
    for (int i = tid; i < HH * 2 * HH; i += 256) { int o = i >> 7, k = i & 127; Wt[k][o] = W[i]; }
    int row = tid >> 2, kq = tid & 3;
    int tx = tid & 15, ty = tid >> 4;
    float acc[4][4] = {};
    __syncthreads();
    {
        const float4* src = (const float4*)(X + (r0 + row) * HH + kq * 16);
#pragma unroll
        for (int j = 0; j < 4; ++j) {
            float4 v = src[j];
            As[kq * 16 + j * 4 + 0][row] = v.x;
            As[kq * 16 + j * 4 + 1][row] = v.y;
            As[kq * 16 + j * 4 + 2][row] = v.z;
            As[kq * 16 + j * 4 + 3][row] = v.w;
        }
    }
    __syncthreads();
#pragma unroll
    for (int k = 0; k < HH; ++k) {
        float4 av = *(const float4*)&As[k][ty * 4];
        float4 wv = *(const float4*)&Wt[k][tx * 4];
        acc[0][0] += av.x * wv.x; acc[0][1] += av.x * wv.y; acc[0][2] += av.x * wv.z; acc[0][3] += av.x * wv.w;
        acc[1][0] += av.y * wv.x; acc[1][1] += av.y * wv.y; acc[1][2] += av.y * wv.z; acc[1][3] += av.y * wv.w;
        acc[2][0] += av.z * wv.x; acc[2][1] += av.z * wv.y; acc[2][2] += av.z * wv.z; acc[2][3] += av.z * wv.w;
        acc[3][0] += av.w * wv.x; acc[3][1] += av.w * wv.y; acc[3][2] += av.w * wv.z; acc[3][3] += av.w * wv.w;
    }
    __syncthreads();
    {
        const uint4* s = (const uint4*)(XAH + (r0 + row) * HH + kq * 16);
        uint4 u0 = s[0], u1 = s[1];
        unsigned short us[16];
        *(uint4*)us = u0; *(uint4*)(us + 8) = u1;
#pragma unroll
        for (int j = 0; j < 16; ++j)
            As[kq * 16 + j][row] = bf2f(us[j]);
    }
    __syncthreads();
#pragma unroll
    for (int k = 0; k < HH; ++k) {
        float4 av = *(const float4*)&As[k][ty * 4];
        float4 wv = *(const float4*)&Wt[HH + k][tx * 4];
        acc[0][0] += av.x * wv.x; acc[0][1] += av.x * wv.y; acc[0][2] += av.x * wv.z; acc[0][3] += av.x * wv.w;
        acc[1][0] += av.y * wv.x; acc[1][1] += av.y * wv.y; acc[1][2] += av.y * wv.z; acc[1][3] += av.y * wv.w;
        acc[2][0] += av.z * wv.x; acc[2][1] += av.z * wv.y; acc[2][2] += av.z * wv.z; acc[2][3] += av.z * wv.w;
        acc[3][0] += av.w * wv.x; acc[3][1] += av.w * wv.y; acc[3][2] += av.w * wv.z; acc[3][3] += av.w * wv.w;
    }
    float4 bv = *(const float4*)(b + tx * 4);
#pragma unroll
    for (int ii = 0; ii < 4; ++ii) {
        float4 o;
        o.x = fmaxf(acc[ii][0] + bv.x, 0.f);
        o.y = fmaxf(acc[ii][1] + bv.y, 0.f);
        o.z = fmaxf(acc[ii][2] + bv.z, 0.f);
        o.w = fmaxf(acc[ii][3] + bv.w, 0.f);
        *(float4*)(OUT + (r0 + ty * 4 + ii) * HH + tx * 4) = o;
    }
}

// ---------------- GCN xw as tiled GEMM: K=64, 64 cols, no bias ----------------
__global__ __launch_bounds__(256) void k_xw2(const float* __restrict__ IN,
                                             const float* __restrict__ W,
                                             float* __restrict__ OUT) {
    __shared__ float Wt[HH][68];
    __shared__ float As[HH][68];
    int tid = threadIdx.x;
    size_t r0 = (size_t)blockIdx.x * 64;
    for (int i = tid; i < HH * HH; i += 256) { int o = i >> 6, k = i & 63; Wt[k][o] = W[i]; }
    int row = tid >> 2, kq = tid & 3;
    {
        const float4* src = (const float4*)(IN + (r0 + row) * HH + kq * 16);
#pragma unroll
        for (int j = 0; j < 4; ++j) {
            float4 v = src[j];
            As[kq * 16 + j * 4 + 0][row] = v.x;
            As[kq * 16 + j * 4 + 1][row] = v.y;
            As[kq * 16 + j * 4 + 2][row] = v.z;
            As[kq * 16 + j * 4 + 3][row] = v.w;
        }
    }
    __syncthreads();
    int tx = tid & 15, ty = tid >> 4;
    float acc[4][4] = {};
#pragma unroll
    for (int k = 0; k < HH; ++k) {
        float4 av = *(const float4*)&As[k][ty * 4];
        float4 wv = *(const float4*)&Wt[k][tx * 4];
        acc[0][0] += av.x * wv.x; acc[0][1] += av.x * wv.y; acc[0][2] += av.x * wv.z; acc[0][3] += av.x * wv.w;
        acc[1][0] += av.y * wv.x; acc[1][1] += av.y * wv.y; acc[1][2] += av.y * wv.z; acc[1][3] += av.y * wv.w;
        acc[2][0] += av.z * wv.x; acc[2][1] += av.z * wv.y; acc[2][2] += av.z * wv.z; acc[2][3] += av.z * wv.w;
        acc[3][0] += av.w * wv.x; acc[3][1] += av.w * wv.y; acc[3][2] += av.w * wv.z; acc[3][3] += av.w * wv.w;
    }
#pragma unroll
    for (int ii = 0; ii < 4; ++ii) {
        float4 o = make_float4(acc[ii][0], acc[ii][1], acc[ii][2], acc[ii][3]);
        *(float4*)(OUT + (r0 + ty * 4 + ii) * HH + tx * 4) = o;
    }
}

// ---------------- GCN aggregate (CSR) + bias + BN + relu, column-chunked ----------------
__global__ __launch_bounds__(256) void k_agg(const float* __restrict__ XW,
                                             const int* __restrict__ off,
                                             const int* __restrict__ csr_src,
                                             const float* __restrict__ csr_nrm,
                                             const float* __restrict__ bias,
                                             const float* __restrict__ g,
                                             const float* __restrict__ bb,
                                             const float* __restrict__ m,
                                             const float* __restrict__ v,
                                             float* __restrict__ OUT) {
    int dst = blockIdx.x, ch = blockIdx.y, tid = threadIdx.x;
    int base = ch * 1024 + tid * 4;
    float4 acc = make_float4(0.f, 0.f, 0.f, 0.f);
    int beg = off[dst], end = off[dst + 1];
    for (int e = beg; e < end; ++e) {
        int src = csr_src[e];
        float w = csr_nrm[e];
        float4 x = *(const float4*)(XW + (size_t)src * THL + base);
        acc.x += w * x.x; acc.y += w * x.y; acc.z += w * x.z; acc.w += w * x.w;
    }
    int h0 = base & 63;
    float4 bs = *(const float4*)(bias + h0);
    float4 gv = *(const float4*)(g + h0);
    float4 vv = *(const float4*)(v + h0);
    float4 mv = *(const float4*)(m + h0);
    float4 bv = *(const float4*)(bb + h0);
    float4 o;
    o.x = fmaxf((acc.x + bs.x - mv.x) * rsqrtf(vv.x + EPSBN) * gv.x + bv.x, 0.f);
    o.y = fmaxf((acc.y + bs.y - mv.y) * rsqrtf(vv.y + EPSBN) * gv.y + bv.y, 0.f);
    o.z = fmaxf((acc.z + bs.z - mv.z) * rsqrtf(vv.z + EPSBN) * gv.z + bv.z, 0.f);
    o.w = fmaxf((acc.w + bs.w - mv.w) * rsqrtf(vv.w + EPSBN) * gv.w + bv.w, 0.f);
    *(float4*)(OUT + (size_t)dst * THL + base) = o;
}

// ---------------- 12-wave gate-split pipelined 2-layer GRU: one block per node ----------------
// R16: each wave = ONE (matrix, gate) pair -> 64 weights/lane (the array size the
// compiler has ALWAYS kept in VGPRs: k_gi=84 VGPR). R12/R14/R15 showed 192+ float
// arrays spill regardless of structure (VGPR 108-112, scratch-bound 370us).
// Pipeline slots: stage A = 12 parallel gate-matvecs {gi0(t), rec0(t), gi1(t-1),
// rec1(t-1)}; stage B = 2 elementwise combines (waves 0, 6). h0/h1 single-buffered
// (producer B / consumer A barrier-separated).
__global__ __launch_bounds__(768, 1) void k_gru12(const float* __restrict__ IN,
                                                  const float* __restrict__ wih0, const float* __restrict__ whh0,
                                                  const float* __restrict__ bih0, const float* __restrict__ bhh0,
                                                  const float* __restrict__ wih1, const float* __restrict__ whh1,
                                                  const float* __restrict__ bih1, const float* __restrict__ bhh1,
                                                  float* __restrict__ hout) {
    __shared__ float h0buf[64];
    __shared__ float h1buf[64];
    __shared__ float gbuf[12][64];
    int tid = threadIdx.x;
    int wid = tid >> 6, j = tid & 63;
    int n = blockIdx.x;
    int mat = wid / 3;          // 0: wih0, 1: whh0, 2: wih1, 3: whh1
    int gate = wid % 3;         // 0: r, 1: z, 2: n
    const float* WM = (mat == 0) ? wih0 : (mat == 1) ? whh0 : (mat == 2) ? wih1 : whh1;
    const float* BM = (mat == 0) ? bih0 : (mat == 1) ? bhh0 : (mat == 2) ? bih1 : bhh1;
    int row = gate * 64 + j;
    float w[64];
    const float4* w4 = (const float4*)(WM + (size_t)row * HH);
#pragma unroll
    for (int q = 0; q < 16; ++q) {
        float4 a = w4[q];
        w[4 * q + 0] = a.x; w[4 * q + 1] = a.y; w[4 * q + 2] = a.z; w[4 * q + 3] = a.w;
    }
    float bias = BM[row];
    const float* xb = IN + (size_t)n * TT * HH;
    if (tid < 64) h0buf[tid] = 0.f;
    else if (tid < 128) h1buf[tid - 64] = 0.f;
    __syncthreads();
#pragma unroll 1
    for (int t = 0; t <= TT; ++t) {
        // ---- stage A: 12 gate-matvecs (wave-uniform act) ----
        bool act = (mat <= 1) ? (t < TT) : (t >= 1);
        if (act) {
            float src;
            if (mat == 0)      src = xb[(size_t)t * HH + j];   // x_t
            else if (mat == 3) src = h1buf[j];                 // h1(t-2)
            else               src = h0buf[j];                 // h0(t-1)
            float acc = bias;
#pragma unroll
            for (int k = 0; k < 64; ++k) {
                float s = rdlane(src, k);
                acc += s * w[k];
            }
            gbuf[wid][j] = acc;
        }
        __syncthreads();
        // ---- stage B: combines ----
        if (wid == 0 && t < TT) {
            float r = fsigmoid(gbuf[0][j] + gbuf[3][j]);
            float z = fsigmoid(gbuf[1][j] + gbuf[4][j]);
            float nn2 = tanhf(gbuf[2][j] + r * gbuf[5][j]);
            h0buf[j] = (1.f - z) * nn2 + z * h0buf[j];
        }
        if (wid == 6 && t >= 1) {
            float r = fsigmoid(gbuf[6][j] + gbuf[9][j]);
            float z = fsigmoid(gbuf[7][j] + gbuf[10][j]);
            float nn2 = tanhf(gbuf[8][j] + r * gbuf[11][j]);
            float hnew = (1.f - z) * nn2 + z * h1buf[j];
            h1buf[j] = hnew;
            if (t == TT) hout[(size_t)n * HH + j] = hnew;
        }
        __syncthreads();
    }
}

// ---------------- head: BN + relu + linear + log_softmax ----------------
__global__ __launch_bounds__(256) void k_head(const float* __restrict__ Hf,
                                              const float* __restrict__ g, const float* __restrict__ b,
                                              const float* __restrict__ m, const float* __restrict__ v,
                                              const float* __restrict__ W, const float* __restrict__ wb,
                                              float* __restrict__ out) {
    __shared__ float hb[4][HH];
    __shared__ float lg[4][CC];
    int tid = threadIdx.x;
    int n0 = blockIdx.x * 4;
    int wv = tid >> 6, lane = tid & 63;
    int n = n0 + wv;
    float x = Hf[(size_t)n * HH + lane];
    x = (x - m[lane]) * rsqrtf(v[lane] + EPSBN) * g[lane] + b[lane];
    hb[wv][lane] = fmaxf(x, 0.f);
    __syncthreads();
    if (tid < 4 * CC) {
        int nn = tid / CC, c = tid % CC;
        float acc = wb[c];
        for (int f = 0; f < HH; ++f) acc += hb[nn][f] * W[c * HH + f];
        lg[nn][c] = acc;
    }
    __syncthreads();
    if (tid < 4 * CC) {
        int nn = tid / CC, c = tid % CC;
        float mx = -1e30f;
#pragma unroll
        for (int i = 0; i < CC; ++i) mx = fmaxf(mx, lg[nn][i]);
        float s = 0.f;
#pragma unroll
        for (int i = 0; i < CC; ++i) s += __expf(lg[nn][i] - mx);
        out[(size_t)(n0 + nn) * CC + c] = lg[nn][c] - mx - __logf(s);
    }
}

// ---------------- launch ----------------
extern "C" void kernel_launch(void* const* d_in, const int* in_sizes, int n_in,
                              void* d_out, int out_size, void* d_ws, size_t ws_size,
                              hipStream_t stream) {
    const float* x_seq     = (const float*)d_in[0];
    const int*   edge_idx  = (const int*)d_in[1];
    const float* edge_w    = (const float*)d_in[2];
    const float* causal_w  = (const float*)d_in[3];
    const float* lin_in_w  = (const float*)d_in[4];
    const float* lin_in_b  = (const float*)d_in[5];
    const float* fusion_w  = (const float*)d_in[6];
    const float* fusion_b  = (const float*)d_in[7];
    const float* gcn_w0    = (const float*)d_in[8];
    const float* gcn_b0    = (const float*)d_in[9];
    const float* gcn_w1    = (const float*)d_in[10];
    const float* gcn_b1    = (const float*)d_in[11];
    const float* bn0_g = (const float*)d_in[12], *bn0_b = (const float*)d_in[13];
    const float* bn0_m = (const float*)d_in[14], *bn0_v = (const float*)d_in[15];
    const float* bn1_g = (const float*)d_in[16], *bn1_b = (const float*)d_in[17];
    const float* bn1_m = (const float*)d_in[18], *bn1_v = (const float*)d_in[19];
    const float* wih0 = (const float*)d_in[20], *whh0 = (const float*)d_in[21];
    const float* bih0 = (const float*)d_in[22], *bhh0 = (const float*)d_in[23];
    const float* wih1 = (const float*)d_in[24], *whh1 = (const float*)d_in[25];
    const float* bih1 = (const float*)d_in[26], *bhh1 = (const float*)d_in[27];
    const float* bno_g = (const float*)d_in[28], *bno_b = (const float*)d_in[29];
    const float* bno_m = (const float*)d_in[30], *bno_v = (const float*)d_in[31];
    const float* lout_w = (const float*)d_in[32], *lout_b = (const float*)d_in[33];
    float* out = (float*)d_out;

    float* wsf = (float*)d_ws;
    unsigned short* WCH = (unsigned short*)(wsf + OFF_WC);
    float* XA  = wsf + OFF_XA;
    float* XB  = wsf + OFF_XB;
    float* XC  = wsf + OFF_XC;
    unsigned short* XAT = (unsigned short*)(wsf + OFF_XC);
    unsigned short* XBH = (unsigned short*)(wsf + OFF_XB);   // bf16 x_agg (gemm C)
    float* DEG = wsf + OFF_DEG;
    int* CNT   = (int*)(wsf + OFF_CNT);
    int* CUR   = (int*)(wsf + OFF_CUR);
    int* OFFP  = (int*)(wsf + OFF_OFF);
    int* CSRS  = (int*)(wsf + OFF_CSRS);
    float* CSRN = wsf + OFF_CSRN;
    float* HST  = wsf + OFF_HST;

    // CSR + degree build
    k_zero<<<8, 256, 0, stream>>>(CNT, CUR, DEG);
    k_count<<<(ETOT + 255) / 256, 256, 0, stream>>>(edge_idx, edge_w, CNT, DEG);
    k_scan<<<1, 1024, 0, stream>>>(CNT, OFFP);
    k_fill<<<(ETOT + 255) / 256, 256, 0, stream>>>(edge_idx, edge_w, DEG, OFFP, CUR, CSRS, CSRN);

    hipMemsetAsync(WCH, 0, (size_t)2048 * 2048 * 2, stream);
    k_softmax<<<NN, 256, 0, stream>>>(causal_w, WCH);
    // lin_in -> XA [N,T,H] fp32
    k_lin2<<<NN, 256, 0, stream>>>(x_seq, lin_in_w, lin_in_b, XA);
    // transpose+cast: XA -> XAh_t bf16 [4096][2048]
    dim3 tg(THL / 64, 2048 / 64);
    k_tr<<<tg, 256, 0, stream>>>(XA, XAT);
    // x_agg = WCh @ X (MFMA bf16) -> XBH (bf16)
    dim3 gg(THL / 128, 2048 / 128);
    k_gemm_bf<<<gg, 256, 0, stream>>>(WCH, XAT, XBH);
    // fusion -> XC  (X fp32 + XAgg bf16)
    k_fus2<<<NN, 256, 0, stream>>>(XA, XBH, fusion_w, fusion_b, XC);
    // GCN layer 0: XC -> XB (xw) -> XA (agg+bn+relu)
    k_xw2<<<NN, 256, 0, stream>>>(XC, gcn_w0, XB);
    dim3 ag(NN, 4);
    k_agg<<<ag, 256, 0, stream>>>(XB, OFFP, CSRS, CSRN, gcn_b0, bn0_g, bn0_b, bn0_m, bn0_v, XA);
    // GCN layer 1: XA -> XB -> XC
    k_xw2<<<NN, 256, 0, stream>>>(XA, gcn_w1, XB);
    k_agg<<<ag, 256, 0, stream>>>(XB, OFFP, CSRS, CSRN, gcn_b1, bn1_g, bn1_b, bn1_m, bn1_v, XC);

    // 12-wave gate-split pipelined 2-layer GRU: XC -> final h in HST (single dispatch)
    k_gru12<<<NN, 768, 0, stream>>>(XC, wih0, whh0, bih0, bhh0,
                                    wih1, whh1, bih1, bhh1, HST);

    // head
    k_head<<<NN / 4, 256, 0, stream>>>(HST, bno_g, bno_b, bno_m, bno_v, lout_w, lout_b, out);
}

// Round 18
// 695.482 us; speedup vs baseline: 1.4111x; 1.4111x over previous
//
#include <hip/hip_runtime.h>
#include <hip/hip_bf16.h>
#include <math.h>

#define TT 64
#define NN 2000
#define FIN 32
#define HH 64
#define CC 10
#define EE 32000
#define ETOT 34000   // E + N self loops
#define THL 4096     // T*H
#define EPSBN 1e-5f

// ---------------- workspace layout (float offsets) ----------------
#define OFF_WC   0u          // WCh bf16 [2048][2048]
#define OFF_XA   4000000u    // 8,192,000  [N,T,H] fp32
#define OFF_XB   12192000u   // 8,192,000  (x_agg bf16 C; then xw bf16 scratch)
#define OFF_XC   20384000u   // 8,192,000  (first: XAh_t bf16 [4096][2048]; then fusion out fp32)
#define OFF_DEG  28576000u   // 2048
#define OFF_H1   28578048u   // 128,000 (unused)
#define OFF_CNT  28706048u   // int 2048
#define OFF_CUR  28708096u   // int 2048
#define OFF_OFF  28710144u   // int 2064
#define OFF_CSRS 28712208u   // int 34016
#define OFF_CSRN 28746224u   // float 34016
#define OFF_HST  28780240u   // float 128,000  (GRU h-state)

typedef __attribute__((ext_vector_type(8))) short short8v;
typedef __attribute__((ext_vector_type(4))) float f32x4;

__device__ __forceinline__ float fsigmoid(float x) { return 1.f / (1.f + __expf(-x)); }
__device__ __forceinline__ unsigned short f2bf(float f) {
    __hip_bfloat16 h = __float2bfloat16(f);
    return *reinterpret_cast<unsigned short*>(&h);
}
__device__ __forceinline__ float bf2f(unsigned short u) {
    unsigned int x = ((unsigned int)u) << 16;
    return __int_as_float(x);
}
__device__ __forceinline__ float rdlane(float v, int k) {
    return __int_as_float(__builtin_amdgcn_readlane(__float_as_int(v), k));
}

// ---------------- CSR build ----------------
__global__ void k_zero(int* cnt, int* cur, float* deg) {
    int i = blockIdx.x * 256 + threadIdx.x;
    if (i < 2048) { cnt[i] = 0; cur[i] = 0; deg[i] = 0.f; }
}

__global__ void k_count(const int* __restrict__ ei, const float* __restrict__ ew,
                        int* cnt, float* deg) {
    int e = blockIdx.x * 256 + threadIdx.x;
    if (e < ETOT) {
        int dst; float w;
        if (e < EE) { dst = ei[EE + e]; w = ew[e]; }
        else        { dst = e - EE;     w = 1.f; }
        atomicAdd(&cnt[dst], 1);
        atomicAdd(&deg[dst], w);
    }
}

__global__ __launch_bounds__(1024) void k_scan(const int* __restrict__ cnt, int* off) {
    __shared__ int s[2048];
    int tid = threadIdx.x;
    s[tid]        = (tid        < NN) ? cnt[tid]        : 0;
    s[tid + 1024] = (tid + 1024 < NN) ? cnt[tid + 1024] : 0;
    __syncthreads();
    for (int d = 1; d < 2048; d <<= 1) {
        int idx = (tid + 1) * (d << 1) - 1;
        if (idx < 2048) s[idx] += s[idx - d];
        __syncthreads();
    }
    if (tid == 0) s[2047] = 0;
    __syncthreads();
    for (int d = 1024; d >= 1; d >>= 1) {
        int idx = (tid + 1) * (d << 1) - 1;
        if (idx < 2048) { int t = s[idx - d]; s[idx - d] = s[idx]; s[idx] += t; }
        __syncthreads();
    }
    off[tid] = s[tid];
    off[tid + 1024] = s[tid + 1024];
}

__global__ void k_fill(const int* __restrict__ ei, const float* __restrict__ ew,
                       const float* __restrict__ deg, const int* __restrict__ off,
                       int* cur, int* csr_src, float* csr_nrm) {
    int e = blockIdx.x * 256 + threadIdx.x;
    if (e < ETOT) {
        int src, dst; float w;
        if (e < EE) { src = ei[e]; dst = ei[EE + e]; w = ew[e]; }
        else        { src = dst = e - EE;            w = 1.f; }
        float ds = rsqrtf(fmaxf(deg[src], 1e-12f));
        float dd = rsqrtf(fmaxf(deg[dst], 1e-12f));
        int pos = off[dst] + atomicAdd(&cur[dst], 1);
        csr_src[pos] = src;
        csr_nrm[pos] = ds * w * dd;
    }
}

// ---------------- softmax over causal_weight rows -> bf16 WCh [2048 stride] ----------------
__global__ __launch_bounds__(256) void k_softmax(const float* __restrict__ CW,
                                                 unsigned short* __restrict__ WCH) {
    __shared__ float row[NN];
    __shared__ float red[256];
    int r = blockIdx.x, tid = threadIdx.x;
    const float* in = CW + (size_t)r * NN;
    float mx = -1e30f;
    for (int i = tid; i < NN; i += 256) { float v = in[i]; row[i] = v; mx = fmaxf(mx, v); }
    red[tid] = mx; __syncthreads();
    for (int s = 128; s > 0; s >>= 1) {
        if (tid < s) red[tid] = fmaxf(red[tid], red[tid + s]);
        __syncthreads();
    }
    mx = red[0]; __syncthreads();
    float sm = 0.f;
    for (int i = tid; i < NN; i += 256) { float e = __expf(row[i] - mx); row[i] = e; sm += e; }
    red[tid] = sm; __syncthreads();
    for (int s = 128; s > 0; s >>= 1) {
        if (tid < s) red[tid] += red[tid + s];
        __syncthreads();
    }
    float inv = 1.f / red[0];
    unsigned short* out = WCH + (size_t)r * 2048;
    for (int i = tid; i < 2048; i += 256)
        out[i] = (i < NN) ? f2bf(row[i] * inv) : (unsigned short)0;
}

// ---------------- lin_in as tiled GEMM: rows=(n,t), K=32, 64 cols ----------------
__global__ __launch_bounds__(256) void k_lin2(const float* __restrict__ XS,
                                              const float* __restrict__ W,
                                              const float* __restrict__ b,
                                              float* __restrict__ OUT) {
    __shared__ float Wt[FIN][68];   // [k][o]
    __shared__ float As[FIN][68];   // [k][row]
    int tid = threadIdx.x;
    int n = blockIdx.x;
    for (int i = tid; i < HH * FIN; i += 256) { int o = i >> 5, k = i & 31; Wt[k][o] = W[i]; }
    int row = tid >> 2, kq = tid & 3;   // row = t
    {
        const float4* src = (const float4*)(XS + ((size_t)row * NN + n) * FIN + kq * 8);
        float4 v0 = src[0], v1 = src[1];
        As[kq * 8 + 0][row] = v0.x; As[kq * 8 + 1][row] = v0.y;
        As[kq * 8 + 2][row] = v0.z; As[kq * 8 + 3][row] = v0.w;
        As[kq * 8 + 4][row] = v1.x; As[kq * 8 + 5][row] = v1.y;
        As[kq * 8 + 6][row] = v1.z; As[kq * 8 + 7][row] = v1.w;
    }
    __syncthreads();
    int tx = tid & 15, ty = tid >> 4;
    float acc[4][4] = {};
#pragma unroll
    for (int k = 0; k < FIN; ++k) {
        float4 av = *(const float4*)&As[k][ty * 4];
        float4 wv = *(const float4*)&Wt[k][tx * 4];
        acc[0][0] += av.x * wv.x; acc[0][1] += av.x * wv.y; acc[0][2] += av.x * wv.z; acc[0][3] += av.x * wv.w;
        acc[1][0] += av.y * wv.x; acc[1][1] += av.y * wv.y; acc[1][2] += av.y * wv.z; acc[1][3] += av.y * wv.w;
        acc[2][0] += av.z * wv.x; acc[2][1] += av.z * wv.y; acc[2][2] += av.z * wv.z; acc[2][3] += av.z * wv.w;
        acc[3][0] += av.w * wv.x; acc[3][1] += av.w * wv.y; acc[3][2] += av.w * wv.z; acc[3][3] += av.w * wv.w;
    }
    float4 bv = *(const float4*)(b + tx * 4);
#pragma unroll
    for (int ii = 0; ii < 4; ++ii) {
        float4 o;
        o.x = fmaxf(acc[ii][0] + bv.x, 0.f);
        o.y = fmaxf(acc[ii][1] + bv.y, 0.f);
        o.z = fmaxf(acc[ii][2] + bv.z, 0.f);
        o.w = fmaxf(acc[ii][3] + bv.w, 0.f);
        *(float4*)(OUT + ((size_t)n * TT + ty * 4 + ii) * HH + tx * 4) = o;
    }
}

// ---------------- transpose + bf16 cast ----------------
__global__ __launch_bounds__(256) void k_tr(const float* __restrict__ X,
                                            unsigned short* __restrict__ XT) {
    __shared__ unsigned short tile[64][65];
    int cb = blockIdx.x * 64;
    int kb = blockIdx.y * 64;
    int tid = threadIdx.x;
    int r = tid >> 2, cq = tid & 3;
    const float4* src = (const float4*)(X + (size_t)(kb + r) * THL + cb + cq * 16);
#pragma unroll
    for (int j = 0; j < 4; ++j) {
        float4 v = src[j];
        tile[cq * 16 + j * 4 + 0][r] = f2bf(v.x);
        tile[cq * 16 + j * 4 + 1][r] = f2bf(v.y);
        tile[cq * 16 + j * 4 + 2][r] = f2bf(v.z);
        tile[cq * 16 + j * 4 + 3][r] = f2bf(v.w);
    }
    __syncthreads();
    int cl = tid >> 2, kq = tid & 3;
    unsigned short tmp[16];
#pragma unroll
    for (int j = 0; j < 16; ++j) tmp[j] = tile[cl][kq * 16 + j];
    unsigned short* dst = XT + (size_t)(cb + cl) * 2048 + kb + kq * 16;
    *(uint4*)dst = *(uint4*)tmp;
    *(uint4*)(dst + 8) = *(uint4*)(tmp + 8);
}

// ---------------- bf16 MFMA GEMM: C(bf16)[2000,4096] = WCh @ X (via XAh_t) — FROZEN ----------------
__global__ __launch_bounds__(256, 1) void k_gemm_bf(const unsigned short* __restrict__ A,
                                                    const unsigned short* __restrict__ B,
                                                    unsigned short* __restrict__ CH) {
    __shared__ unsigned short As[128][72];
    __shared__ unsigned short Bs[128][72];
    int tid = threadIdx.x;
    int mb = blockIdx.y * 128, nb = blockIdx.x * 128;
    int w = tid >> 6, lane = tid & 63;
    int wr = w >> 1, wc = w & 1;
    int l15 = lane & 15, l4 = lane >> 4;
    f32x4 acc[4][4] = {};
    int arow = tid >> 3, acol = tid & 7;
    const uint4* ga = (const uint4*)(A + (size_t)(mb + arow) * 2048 + acol * 8);
    const uint4* gb = (const uint4*)(B + (size_t)(nb + arow) * 2048 + acol * 8);
    uint4 va[4], vb[4];
#pragma unroll
    for (int i = 0; i < 4; ++i) { va[i] = ga[(size_t)i * 8192]; vb[i] = gb[(size_t)i * 8192]; }
    ga += 8; gb += 8;
    for (int kt = 0; kt < 32; ++kt) {
        __syncthreads();
#pragma unroll
        for (int i = 0; i < 4; ++i) {
            *(uint4*)&As[arow + i * 32][acol * 8] = va[i];
            *(uint4*)&Bs[arow + i * 32][acol * 8] = vb[i];
        }
        __syncthreads();
        if (kt < 31) {
#pragma unroll
            for (int i = 0; i < 4; ++i) { va[i] = ga[(size_t)i * 8192]; vb[i] = gb[(size_t)i * 8192]; }
            ga += 8; gb += 8;
        }
#pragma unroll
        for (int kk = 0; kk < 2; ++kk) {
            short8v af[4], bfr[4];
#pragma unroll
            for (int f = 0; f < 4; ++f) {
                af[f]  = *(const short8v*)&As[wr * 64 + f * 16 + l15][kk * 32 + l4 * 8];
                bfr[f] = *(const short8v*)&Bs[wc * 64 + f * 16 + l15][kk * 32 + l4 * 8];
            }
#pragma unroll
            for (int fm = 0; fm < 4; ++fm)
#pragma unroll
                for (int fn = 0; fn < 4; ++fn)
                    acc[fm][fn] = __builtin_amdgcn_mfma_f32_16x16x32_bf16(af[fm], bfr[fn], acc[fm][fn], 0, 0, 0);
        }
    }
    unsigned short* epi = (unsigned short*)(&As[0][0]) + (size_t)w * (16 * 72);
    int erow8 = lane >> 3;
    int ecol8 = lane & 7;
#pragma unroll
    for (int fm = 0; fm < 4; ++fm) {
        __syncthreads();
#pragma unroll
        for (int fn = 0; fn < 4; ++fn)
#pragma unroll
            for (int rr = 0; rr < 4; ++rr)
                epi[(l4 * 4 + rr) * 72 + fn * 16 + l15] = f2bf(acc[fm][fn][rr]);
        __syncthreads();
#pragma unroll
        for (int rh = 0; rh < 2; ++rh) {
            int lrow = rh * 8 + erow8;
            int grow = mb + wr * 64 + fm * 16 + lrow;
            if (grow < NN) {
                *(uint4*)(CH + (size_t)grow * THL + nb + wc * 64 + ecol8 * 8)
                    = *(const uint4*)&epi[lrow * 72 + ecol8 * 8];
            }
        }
    }
}

// ---------------- fusion as tiled GEMM: K=128 (X fp32 + XAgg bf16), 64 cols ----------------
__global__ __launch_bounds__(256) void k_fus2(const float* __restrict__ X,
                                              const unsigned short* __restrict__ XAH,
                                              const float* __restrict__ W,
                                              const float* __restrict__ b,
                                              float* __restrict__ OUT) {
    __shared__ float Wt[2 * HH][68];
    __shared__ float As[HH][68];
    int tid = threadIdx.x;
    size_t r0 = (size_t)blockIdx.x * 64;
    for (int i = tid; i < HH * 2 * HH; i += 256) { int o = i >> 7, k = i & 127; Wt[k][o] = W[i]; }
    int row = tid >> 2, kq = tid & 3;
    int tx = tid & 15, ty = tid >> 4;
    float acc[4][4] = {};
    __syncthreads();
    {
        const float4* src = (const float4*)(X + (r0 + row) * HH + kq * 16);
#pragma unroll
        for (int j = 0; j < 4; ++j) {
            float4 v = src[j];
            As[kq * 16 + j * 4 + 0][row] = v.x;
            As[kq * 16 + j * 4 + 1][row] = v.y;
            As[kq * 16 + j * 4 + 2][row] = v.z;
            As[kq * 16 + j * 4 + 3][row] = v.w;
        }
    }
    __syncthreads();
#pragma unroll
    for (int k = 0; k < HH; ++k) {
        float4 av = *(const float4*)&As[k][ty * 4];
        float4 wv = *(const float4*)&Wt[k][tx * 4];
        acc[0][0] += av.x * wv.x; acc[0][1] += av.x * wv.y; acc[0][2] += av.x * wv.z; acc[0][3] += av.x * wv.w;
        acc[1][0] += av.y * wv.x; acc[1][1] += av.y * wv.y; acc[1][2] += av.y * wv.z; acc[1][3] += av.y * wv.w;
        acc[2][0] += av.z * wv.x; acc[2][1] += av.z * wv.y; acc[2][2] += av.z * wv.z; acc[2][3] += av.z * wv.w;
        acc[3][0] += av.w * wv.x; acc[3][1] += av.w * wv.y; acc[3][2] += av.w * wv.z; acc[3][3] += av.w * wv.w;
    }
    __syncthreads();
    {
        const uint4* s = (const uint4*)(XAH + (r0 + row) * HH + kq * 16);
        uint4 u0 = s[0], u1 = s[1];
        unsigned short us[16];
        *(uint4*)us = u0; *(uint4*)(us + 8) = u1;
#pragma unroll
        for (int j = 0; j < 16; ++j)
            As[kq * 16 + j][row] = bf2f(us[j]);
    }
    __syncthreads();
#pragma unroll
    for (int k = 0; k < HH; ++k) {
        float4 av = *(const float4*)&As[k][ty * 4];
        float4 wv = *(const float4*)&Wt[HH + k][tx * 4];
        acc[0][0] += av.x * wv.x; acc[0][1] += av.x * wv.y; acc[0][2] += av.x * wv.z; acc[0][3] += av.x * wv.w;
        acc[1][0] += av.y * wv.x; acc[1][1] += av.y * wv.y; acc[1][2] += av.y * wv.z; acc[1][3] += av.y * wv.w;
        acc[2][0] += av.z * wv.x; acc[2][1] += av.z * wv.y; acc[2][2] += av.z * wv.z; acc[2][3] += av.z * wv.w;
        acc[3][0] += av.w * wv.x; acc[3][1] += av.w * wv.y; acc[3][2] += av.w * wv.z; acc[3][3] += av.w * wv.w;
    }
    float4 bv = *(const float4*)(b + tx * 4);
#pragma unroll
    for (int ii = 0; ii < 4; ++ii) {
        float4 o;
        o.x = fmaxf(acc[ii][0] + bv.x, 0.f);
        o.y = fmaxf(acc[ii][1] + bv.y, 0.f);
        o.z = fmaxf(acc[ii][2] + bv.z, 0.f);
        o.w = fmaxf(acc[ii][3] + bv.w, 0.f);
        *(float4*)(OUT + (r0 + ty * 4 + ii) * HH + tx * 4) = o;
    }
}

// ---------------- GCN xw as tiled GEMM: K=64, 64 cols, bf16 output ----------------
// R18 fix: output row stride is HH (flat [N*T][H]) — R17 used THL here (64x OOB, crash).
__global__ __launch_bounds__(256) void k_xw2(const float* __restrict__ IN,
                                             const float* __restrict__ W,
                                             unsigned short* __restrict__ OUT) {
    __shared__ float Wt[HH][68];
    __shared__ float As[HH][68];
    int tid = threadIdx.x;
    size_t r0 = (size_t)blockIdx.x * 64;
    for (int i = tid; i < HH * HH; i += 256) { int o = i >> 6, k = i & 63; Wt[k][o] = W[i]; }
    int row = tid >> 2, kq = tid & 3;
    {
        const float4* src = (const float4*)(IN + (r0 + row) * HH + kq * 16);
#pragma unroll
        for (int j = 0; j < 4; ++j) {
            float4 v = src[j];
            As[kq * 16 + j * 4 + 0][row] = v.x;
            As[kq * 16 + j * 4 + 1][row] = v.y;
            As[kq * 16 + j * 4 + 2][row] = v.z;
            As[kq * 16 + j * 4 + 3][row] = v.w;
        }
    }
    __syncthreads();
    int tx = tid & 15, ty = tid >> 4;
    float acc[4][4] = {};
#pragma unroll
    for (int k = 0; k < HH; ++k) {
        float4 av = *(const float4*)&As[k][ty * 4];
        float4 wv = *(const float4*)&Wt[k][tx * 4];
        acc[0][0] += av.x * wv.x; acc[0][1] += av.x * wv.y; acc[0][2] += av.x * wv.z; acc[0][3] += av.x * wv.w;
        acc[1][0] += av.y * wv.x; acc[1][1] += av.y * wv.y; acc[1][2] += av.y * wv.z; acc[1][3] += av.y * wv.w;
        acc[2][0] += av.z * wv.x; acc[2][1] += av.z * wv.y; acc[2][2] += av.z * wv.z; acc[2][3] += av.z * wv.w;
        acc[3][0] += av.w * wv.x; acc[3][1] += av.w * wv.y; acc[3][2] += av.w * wv.z; acc[3][3] += av.w * wv.w;
    }
#pragma unroll
    for (int ii = 0; ii < 4; ++ii) {
        unsigned int p0 = (unsigned int)f2bf(acc[ii][0]) | ((unsigned int)f2bf(acc[ii][1]) << 16);
        unsigned int p1 = (unsigned int)f2bf(acc[ii][2]) | ((unsigned int)f2bf(acc[ii][3]) << 16);
        uint2 pk; pk.x = p0; pk.y = p1;
        *(uint2*)(OUT + (r0 + ty * 4 + ii) * HH + tx * 4) = pk;
    }
}

// ---------------- GCN aggregate (CSR, bf16 in) + bias + BN + relu ----------------
__global__ __launch_bounds__(256) void k_agg(const unsigned short* __restrict__ XW,
                                             const int* __restrict__ off,
                                             const int* __restrict__ csr_src,
                                             const float* __restrict__ csr_nrm,
                                             const float* __restrict__ bias,
                                             const float* __restrict__ g,
                                             const float* __restrict__ bb,
                                             const float* __restrict__ m,
                                             const float* __restrict__ v,
                                             float* __restrict__ OUT) {
    int dst = blockIdx.x, ch = blockIdx.y, tid = threadIdx.x;
    int base = ch * 1024 + tid * 4;
    float4 acc = make_float4(0.f, 0.f, 0.f, 0.f);
    int beg = off[dst], end = off[dst + 1];
    for (int e = beg; e < end; ++e) {
        int src = csr_src[e];
        float w = csr_nrm[e];
        uint2 u = *(const uint2*)(XW + (size_t)src * THL + base);
        acc.x += w * bf2f((unsigned short)(u.x & 0xffff));
        acc.y += w * bf2f((unsigned short)(u.x >> 16));
        acc.z += w * bf2f((unsigned short)(u.y & 0xffff));
        acc.w += w * bf2f((unsigned short)(u.y >> 16));
    }
    int h0 = base & 63;
    float4 bs = *(const float4*)(bias + h0);
    float4 gv = *(const float4*)(g + h0);
    float4 vv = *(const float4*)(v + h0);
    float4 mv = *(const float4*)(m + h0);
    float4 bv = *(const float4*)(bb + h0);
    float4 o;
    o.x = fmaxf((acc.x + bs.x - mv.x) * rsqrtf(vv.x + EPSBN) * gv.x + bv.x, 0.f);
    o.y = fmaxf((acc.y + bs.y - mv.y) * rsqrtf(vv.y + EPSBN) * gv.y + bv.y, 0.f);
    o.z = fmaxf((acc.z + bs.z - mv.z) * rsqrtf(vv.z + EPSBN) * gv.z + bv.z, 0.f);
    o.w = fmaxf((acc.w + bs.w - mv.w) * rsqrtf(vv.w + EPSBN) * gv.w + bv.w, 0.f);
    *(float4*)(OUT + (size_t)dst * THL + base) = o;
}

// ---------------- 4-wave pipelined 2-layer GRU (R15 best-known) ----------------
__global__ __launch_bounds__(256, 1) void k_gru4(const float* __restrict__ IN,
                                                 const float* __restrict__ wih0, const float* __restrict__ whh0,
                                                 const float* __restrict__ bih0, const float* __restrict__ bhh0,
                                                 const float* __restrict__ wih1, const float* __restrict__ whh1,
                                                 const float* __restrict__ bih1, const float* __restrict__ bhh1,
                                                 float* __restrict__ hout) {
    __shared__ float qgi0[2][192];
    __shared__ float qh0[2][64];
    __shared__ float qgi1[2][192];
    int tid = threadIdx.x;
    int wid = tid >> 6, j = tid & 63;
    int n = blockIdx.x;
    const float* WM = (wid == 0) ? wih0 : (wid == 1) ? whh0 : (wid == 2) ? wih1 : whh1;
    const float* BM = (wid == 0) ? bih0 : (wid == 1) ? bhh0 : (wid == 2) ? bih1 : bhh1;
    float w0[64], w1[64], w2[64];
    const float4* w4 = (const float4*)WM;
#pragma unroll
    for (int q = 0; q < 16; ++q) {
        float4 a = w4[(size_t)j * 16 + q];
        float4 b = w4[(size_t)(64 + j) * 16 + q];
        float4 c = w4[(size_t)(128 + j) * 16 + q];
        w0[4 * q + 0] = a.x; w0[4 * q + 1] = a.y; w0[4 * q + 2] = a.z; w0[4 * q + 3] = a.w;
        w1[4 * q + 0] = b.x; w1[4 * q + 1] = b.y; w1[4 * q + 2] = b.z; w1[4 * q + 3] = b.w;
        w2[4 * q + 0] = c.x; w2[4 * q + 1] = c.y; w2[4 * q + 2] = c.z; w2[4 * q + 3] = c.w;
    }
    float b0 = BM[j], b1 = BM[64 + j], b2 = BM[128 + j];
    float h = 0.f;
    const float* xb = IN + (size_t)n * TT * HH;
    for (int i = tid; i < 2 * 192; i += 256) { ((float*)qgi0)[i] = 0.f; ((float*)qgi1)[i] = 0.f; }
    if (tid < 128) ((float*)qh0)[tid] = 0.f;
    __syncthreads();
#pragma unroll 1
    for (int t = 0; t < TT + 3; ++t) {
        int tt = t - wid;
        bool act = (tt >= 0) && (tt < TT);
        int sl = tt & 1;
        float src;
        if (wid == 0)      src = act ? xb[(size_t)tt * HH + j] : 0.f;
        else if (wid == 1) src = h;
        else if (wid == 2) src = qh0[sl][j];
        else               src = h;
        float a0 = b0, a1 = b1, a2 = b2;
#pragma unroll
        for (int k = 0; k < 64; ++k) {
            float s = rdlane(src, k);
            a0 += s * w0[k]; a1 += s * w1[k]; a2 += s * w2[k];
        }
        if (act) {
            if (wid == 0) {
                qgi0[sl][j] = a0; qgi0[sl][64 + j] = a1; qgi0[sl][128 + j] = a2;
            } else if (wid == 1) {
                float gr = qgi0[sl][j], gz = qgi0[sl][64 + j], gn = qgi0[sl][128 + j];
                float r = fsigmoid(gr + a0);
                float z = fsigmoid(gz + a1);
                float nn2 = tanhf(gn + r * a2);
                h = (1.f - z) * nn2 + z * h;
                qh0[sl][j] = h;
            } else if (wid == 2) {
                qgi1[sl][j] = a0; qgi1[sl][64 + j] = a1; qgi1[sl][128 + j] = a2;
            } else {
                float gr = qgi1[sl][j], gz = qgi1[sl][64 + j], gn = qgi1[sl][128 + j];
                float r = fsigmoid(gr + a0);
                float z = fsigmoid(gz + a1);
                float nn2 = tanhf(gn + r * a2);
                h = (1.f - z) * nn2 + z * h;
            }
        }
        __syncthreads();
    }
    if (wid == 3) hout[(size_t)n * HH + j] = h;
}

// ---------------- head: BN + relu + linear + log_softmax ----------------
__global__ __launch_bounds__(256) void k_head(const float* __restrict__ Hf,
                                              const float* __restrict__ g, const float* __restrict__ b,
                                              const float* __restrict__ m, const float* __restrict__ v,
                                              const float* __restrict__ W, const float* __restrict__ wb,
                                              float* __restrict__ out) {
    __shared__ float hb[4][HH];
    __shared__ float lg[4][CC];
    int tid = threadIdx.x;
    int n0 = blockIdx.x * 4;
    int wv = tid >> 6, lane = tid & 63;
    int n = n0 + wv;
    float x = Hf[(size_t)n * HH + lane];
    x = (x - m[lane]) * rsqrtf(v[lane] + EPSBN) * g[lane] + b[lane];
    hb[wv][lane] = fmaxf(x, 0.f);
    __syncthreads();
    if (tid < 4 * CC) {
        int nn = tid / CC, c = tid % CC;
        float acc = wb[c];
        for (int f = 0; f < HH; ++f) acc += hb[nn][f] * W[c * HH + f];
        lg[nn][c] = acc;
    }
    __syncthreads();
    if (tid < 4 * CC) {
        int nn = tid / CC, c = tid % CC;
        float mx = -1e30f;
#pragma unroll
        for (int i = 0; i < CC; ++i) mx = fmaxf(mx, lg[nn][i]);
        float s = 0.f;
#pragma unroll
        for (int i = 0; i < CC; ++i) s += __expf(lg[nn][i] - mx);
        out[(size_t)(n0 + nn) * CC + c] = lg[nn][c] - mx - __logf(s);
    }
}

// ---------------- launch ----------------
extern "C" void kernel_launch(void* const* d_in, const int* in_sizes, int n_in,
                              void* d_out, int out_size, void* d_ws, size_t ws_size,
                              hipStream_t stream) {
    const float* x_seq     = (const float*)d_in[0];
    const int*   edge_idx  = (const int*)d_in[1];
    const float* edge_w    = (const float*)d_in[2];
    const float* causal_w  = (const float*)d_in[3];
    const float* lin_in_w  = (const float*)d_in[4];
    const float* lin_in_b  = (const float*)d_in[5];
    const float* fusion_w  = (const float*)d_in[6];
    const float* fusion_b  = (const float*)d_in[7];
    const float* gcn_w0    = (const float*)d_in[8];
    const float* gcn_b0    = (const float*)d_in[9];
    const float* gcn_w1    = (const float*)d_in[10];
    const float* gcn_b1    = (const float*)d_in[11];
    const float* bn0_g = (const float*)d_in[12], *bn0_b = (const float*)d_in[13];
    const float* bn0_m = (const float*)d_in[14], *bn0_v = (const float*)d_in[15];
    const float* bn1_g = (const float*)d_in[16], *bn1_b = (const float*)d_in[17];
    const float* bn1_m = (const float*)d_in[18], *bn1_v = (const float*)d_in[19];
    const float* wih0 = (const float*)d_in[20], *whh0 = (const float*)d_in[21];
    const float* bih0 = (const float*)d_in[22], *bhh0 = (const float*)d_in[23];
    const float* wih1 = (const float*)d_in[24], *whh1 = (const float*)d_in[25];
    const float* bih1 = (const float*)d_in[26], *bhh1 = (const float*)d_in[27];
    const float* bno_g = (const float*)d_in[28], *bno_b = (const float*)d_in[29];
    const float* bno_m = (const float*)d_in[30], *bno_v = (const float*)d_in[31];
    const float* lout_w = (const float*)d_in[32], *lout_b = (const float*)d_in[33];
    float* out = (float*)d_out;

    float* wsf = (float*)d_ws;
    unsigned short* WCH = (unsigned short*)(wsf + OFF_WC);
    float* XA  = wsf + OFF_XA;
    float* XB  = wsf + OFF_XB;
    float* XC  = wsf + OFF_XC;
    unsigned short* XAT = (unsigned short*)(wsf + OFF_XC);
    unsigned short* XBH = (unsigned short*)(wsf + OFF_XB);   // bf16: x_agg (gemm C), then xw output
    float* DEG = wsf + OFF_DEG;
    int* CNT   = (int*)(wsf + OFF_CNT);
    int* CUR   = (int*)(wsf + OFF_CUR);
    int* OFFP  = (int*)(wsf + OFF_OFF);
    int* CSRS  = (int*)(wsf + OFF_CSRS);
    float* CSRN = wsf + OFF_CSRN;
    float* HST  = wsf + OFF_HST;

    // CSR + degree build
    k_zero<<<8, 256, 0, stream>>>(CNT, CUR, DEG);
    k_count<<<(ETOT + 255) / 256, 256, 0, stream>>>(edge_idx, edge_w, CNT, DEG);
    k_scan<<<1, 1024, 0, stream>>>(CNT, OFFP);
    k_fill<<<(ETOT + 255) / 256, 256, 0, stream>>>(edge_idx, edge_w, DEG, OFFP, CUR, CSRS, CSRN);

    hipMemsetAsync(WCH, 0, (size_t)2048 * 2048 * 2, stream);
    k_softmax<<<NN, 256, 0, stream>>>(causal_w, WCH);
    // lin_in -> XA [N,T,H] fp32
    k_lin2<<<NN, 256, 0, stream>>>(x_seq, lin_in_w, lin_in_b, XA);
    // transpose+cast: XA -> XAh_t bf16 [4096][2048]
    dim3 tg(THL / 64, 2048 / 64);
    k_tr<<<tg, 256, 0, stream>>>(XA, XAT);
    // x_agg = WCh @ X (MFMA bf16) -> XBH (bf16)
    dim3 gg(THL / 128, 2048 / 128);
    k_gemm_bf<<<gg, 256, 0, stream>>>(WCH, XAT, XBH);
    // fusion -> XC  (X fp32 + XAgg bf16)
    k_fus2<<<NN, 256, 0, stream>>>(XA, XBH, fusion_w, fusion_b, XC);
    // GCN layer 0: XC -> XBH (xw, bf16) -> XA (agg+bn+relu, fp32)
    k_xw2<<<NN, 256, 0, stream>>>(XC, gcn_w0, XBH);
    dim3 ag(NN, 4);
    k_agg<<<ag, 256, 0, stream>>>(XBH, OFFP, CSRS, CSRN, gcn_b0, bn0_g, bn0_b, bn0_m, bn0_v, XA);
    // GCN layer 1: XA -> XBH -> XC
    k_xw2<<<NN, 256, 0, stream>>>(XA, gcn_w1, XBH);
    k_agg<<<ag, 256, 0, stream>>>(XBH, OFFP, CSRS, CSRN, gcn_b1, bn1_g, bn1_b, bn1_m, bn1_v, XC);

    // 4-wave pipelined 2-layer GRU: XC -> final h in HST (single dispatch)
    k_gru4<<<NN, 256, 0, stream>>>(XC, wih0, whh0, bih0, bhh0,
                                   wih1, whh1, bih1, bhh1, HST);

    // head
    k_head<<<NN / 4, 256, 0, stream>>>(HST, bno_g, bno_b, bno_m, bno_v, lout_w, lout_b, out);
}

// Round 19
// 510.432 us; speedup vs baseline: 1.9227x; 1.3625x over previous
//
#include <hip/hip_runtime.h>
#include <hip/hip_bf16.h>
#include <math.h>

#define TT 64
#define NN 2000
#define FIN 32
#define HH 64
#define CC 10
#define EE 32000
#define ETOT 34000   // E + N self loops
#define THL 4096     // T*H
#define EPSBN 1e-5f
#define NB 16        // nodes per GRU block (one MFMA M-tile)

// ---------------- workspace layout (float offsets) ----------------
#define OFF_WC   0u          // WCh bf16 [2048][2048]
#define OFF_XA   4000000u    // 8,192,000  [N,T,H] fp32
#define OFF_XB   12192000u   // 8,192,000  (x_agg bf16 C; then xw bf16 scratch)
#define OFF_XC   20384000u   // 8,192,000  (first: XAh_t bf16 [4096][2048]; then fusion out fp32)
#define OFF_DEG  28576000u   // 2048
#define OFF_H1   28578048u   // 128,000 (unused)
#define OFF_CNT  28706048u   // int 2048
#define OFF_CUR  28708096u   // int 2048
#define OFF_OFF  28710144u   // int 2064
#define OFF_CSRS 28712208u   // int 34016
#define OFF_CSRN 28746224u   // float 34016
#define OFF_HST  28780240u   // float 128,000  (GRU h-state)

typedef __attribute__((ext_vector_type(8))) short short8v;
typedef __attribute__((ext_vector_type(4))) float f32x4;

__device__ __forceinline__ float fsigmoid(float x) { return 1.f / (1.f + __expf(-x)); }
__device__ __forceinline__ unsigned short f2bf(float f) {
    __hip_bfloat16 h = __float2bfloat16(f);
    return *reinterpret_cast<unsigned short*>(&h);
}
__device__ __forceinline__ float bf2f(unsigned short u) {
    unsigned int x = ((unsigned int)u) << 16;
    return __int_as_float(x);
}

// ---------------- CSR build ----------------
__global__ void k_zero(int* cnt, int* cur, float* deg) {
    int i = blockIdx.x * 256 + threadIdx.x;
    if (i < 2048) { cnt[i] = 0; cur[i] = 0; deg[i] = 0.f; }
}

__global__ void k_count(const int* __restrict__ ei, const float* __restrict__ ew,
                        int* cnt, float* deg) {
    int e = blockIdx.x * 256 + threadIdx.x;
    if (e < ETOT) {
        int dst; float w;
        if (e < EE) { dst = ei[EE + e]; w = ew[e]; }
        else        { dst = e - EE;     w = 1.f; }
        atomicAdd(&cnt[dst], 1);
        atomicAdd(&deg[dst], w);
    }
}

__global__ __launch_bounds__(1024) void k_scan(const int* __restrict__ cnt, int* off) {
    __shared__ int s[2048];
    int tid = threadIdx.x;
    s[tid]        = (tid        < NN) ? cnt[tid]        : 0;
    s[tid + 1024] = (tid + 1024 < NN) ? cnt[tid + 1024] : 0;
    __syncthreads();
    for (int d = 1; d < 2048; d <<= 1) {
        int idx = (tid + 1) * (d << 1) - 1;
        if (idx < 2048) s[idx] += s[idx - d];
        __syncthreads();
    }
    if (tid == 0) s[2047] = 0;
    __syncthreads();
    for (int d = 1024; d >= 1; d >>= 1) {
        int idx = (tid + 1) * (d << 1) - 1;
        if (idx < 2048) { int t = s[idx - d]; s[idx - d] = s[idx]; s[idx] += t; }
        __syncthreads();
    }
    off[tid] = s[tid];
    off[tid + 1024] = s[tid + 1024];
}

__global__ void k_fill(const int* __restrict__ ei, const float* __restrict__ ew,
                       const float* __restrict__ deg, const int* __restrict__ off,
                       int* cur, int* csr_src, float* csr_nrm) {
    int e = blockIdx.x * 256 + threadIdx.x;
    if (e < ETOT) {
        int src, dst; float w;
        if (e < EE) { src = ei[e]; dst = ei[EE + e]; w = ew[e]; }
        else        { src = dst = e - EE;            w = 1.f; }
        float ds = rsqrtf(fmaxf(deg[src], 1e-12f));
        float dd = rsqrtf(fmaxf(deg[dst], 1e-12f));
        int pos = off[dst] + atomicAdd(&cur[dst], 1);
        csr_src[pos] = src;
        csr_nrm[pos] = ds * w * dd;
    }
}

// ---------------- softmax over causal_weight rows -> bf16 WCh [2048 stride] ----------------
__global__ __launch_bounds__(256) void k_softmax(const float* __restrict__ CW,
                                                 unsigned short* __restrict__ WCH) {
    __shared__ float row[NN];
    __shared__ float red[256];
    int r = blockIdx.x, tid = threadIdx.x;
    const float* in = CW + (size_t)r * NN;
    float mx = -1e30f;
    for (int i = tid; i < NN; i += 256) { float v = in[i]; row[i] = v; mx = fmaxf(mx, v); }
    red[tid] = mx; __syncthreads();
    for (int s = 128; s > 0; s >>= 1) {
        if (tid < s) red[tid] = fmaxf(red[tid], red[tid + s]);
        __syncthreads();
    }
    mx = red[0]; __syncthreads();
    float sm = 0.f;
    for (int i = tid; i < NN; i += 256) { float e = __expf(row[i] - mx); row[i] = e; sm += e; }
    red[tid] = sm; __syncthreads();
    for (int s = 128; s > 0; s >>= 1) {
        if (tid < s) red[tid] += red[tid + s];
        __syncthreads();
    }
    float inv = 1.f / red[0];
    unsigned short* out = WCH + (size_t)r * 2048;
    for (int i = tid; i < 2048; i += 256)
        out[i] = (i < NN) ? f2bf(row[i] * inv) : (unsigned short)0;
}

// ---------------- lin_in as tiled GEMM: rows=(n,t), K=32, 64 cols ----------------
__global__ __launch_bounds__(256) void k_lin2(const float* __restrict__ XS,
                                              const float* __restrict__ W,
                                              const float* __restrict__ b,
                                              float* __restrict__ OUT) {
    __shared__ float Wt[FIN][68];   // [k][o]
    __shared__ float As[FIN][68];   // [k][row]
    int tid = threadIdx.x;
    int n = blockIdx.x;
    for (int i = tid; i < HH * FIN; i += 256) { int o = i >> 5, k = i & 31; Wt[k][o] = W[i]; }
    int row = tid >> 2, kq = tid & 3;   // row = t
    {
        const float4* src = (const float4*)(XS + ((size_t)row * NN + n) * FIN + kq * 8);
        float4 v0 = src[0], v1 = src[1];
        As[kq * 8 + 0][row] = v0.x; As[kq * 8 + 1][row] = v0.y;
        As[kq * 8 + 2][row] = v0.z; As[kq * 8 + 3][row] = v0.w;
        As[kq * 8 + 4][row] = v1.x; As[kq * 8 + 5][row] = v1.y;
        As[kq * 8 + 6][row] = v1.z; As[kq * 8 + 7][row] = v1.w;
    }
    __syncthreads();
    int tx = tid & 15, ty = tid >> 4;
    float acc[4][4] = {};
#pragma unroll
    for (int k = 0; k < FIN; ++k) {
        float4 av = *(const float4*)&As[k][ty * 4];
        float4 wv = *(const float4*)&Wt[k][tx * 4];
        acc[0][0] += av.x * wv.x; acc[0][1] += av.x * wv.y; acc[0][2] += av.x * wv.z; acc[0][3] += av.x * wv.w;
        acc[1][0] += av.y * wv.x; acc[1][1] += av.y * wv.y; acc[1][2] += av.y * wv.z; acc[1][3] += av.y * wv.w;
        acc[2][0] += av.z * wv.x; acc[2][1] += av.z * wv.y; acc[2][2] += av.z * wv.z; acc[2][3] += av.z * wv.w;
        acc[3][0] += av.w * wv.x; acc[3][1] += av.w * wv.y; acc[3][2] += av.w * wv.z; acc[3][3] += av.w * wv.w;
    }
    float4 bv = *(const float4*)(b + tx * 4);
#pragma unroll
    for (int ii = 0; ii < 4; ++ii) {
        float4 o;
        o.x = fmaxf(acc[ii][0] + bv.x, 0.f);
        o.y = fmaxf(acc[ii][1] + bv.y, 0.f);
        o.z = fmaxf(acc[ii][2] + bv.z, 0.f);
        o.w = fmaxf(acc[ii][3] + bv.w, 0.f);
        *(float4*)(OUT + ((size_t)n * TT + ty * 4 + ii) * HH + tx * 4) = o;
    }
}

// ---------------- transpose + bf16 cast ----------------
__global__ __launch_bounds__(256) void k_tr(const float* __restrict__ X,
                                            unsigned short* __restrict__ XT) {
    __shared__ unsigned short tile[64][65];
    int cb = blockIdx.x * 64;
    int kb = blockIdx.y * 64;
    int tid = threadIdx.x;
    int r = tid >> 2, cq = tid & 3;
    const float4* src = (const float4*)(X + (size_t)(kb + r) * THL + cb + cq * 16);
#pragma unroll
    for (int j = 0; j < 4; ++j) {
        float4 v = src[j];
        tile[cq * 16 + j * 4 + 0][r] = f2bf(v.x);
        tile[cq * 16 + j * 4 + 1][r] = f2bf(v.y);
        tile[cq * 16 + j * 4 + 2][r] = f2bf(v.z);
        tile[cq * 16 + j * 4 + 3][r] = f2bf(v.w);
    }
    __syncthreads();
    int cl = tid >> 2, kq = tid & 3;
    unsigned short tmp[16];
#pragma unroll
    for (int j = 0; j < 16; ++j) tmp[j] = tile[cl][kq * 16 + j];
    unsigned short* dst = XT + (size_t)(cb + cl) * 2048 + kb + kq * 16;
    *(uint4*)dst = *(uint4*)tmp;
    *(uint4*)(dst + 8) = *(uint4*)(tmp + 8);
}

// ---------------- bf16 MFMA GEMM: C(bf16)[2000,4096] = WCh @ X (via XAh_t) — FROZEN ----------------
__global__ __launch_bounds__(256, 1) void k_gemm_bf(const unsigned short* __restrict__ A,
                                                    const unsigned short* __restrict__ B,
                                                    unsigned short* __restrict__ CH) {
    __shared__ unsigned short As[128][72];
    __shared__ unsigned short Bs[128][72];
    int tid = threadIdx.x;
    int mb = blockIdx.y * 128, nb = blockIdx.x * 128;
    int w = tid >> 6, lane = tid & 63;
    int wr = w >> 1, wc = w & 1;
    int l15 = lane & 15, l4 = lane >> 4;
    f32x4 acc[4][4] = {};
    int arow = tid >> 3, acol = tid & 7;
    const uint4* ga = (const uint4*)(A + (size_t)(mb + arow) * 2048 + acol * 8);
    const uint4* gb = (const uint4*)(B + (size_t)(nb + arow) * 2048 + acol * 8);
    uint4 va[4], vb[4];
#pragma unroll
    for (int i = 0; i < 4; ++i) { va[i] = ga[(size_t)i * 8192]; vb[i] = gb[(size_t)i * 8192]; }
    ga += 8; gb += 8;
    for (int kt = 0; kt < 32; ++kt) {
        __syncthreads();
#pragma unroll
        for (int i = 0; i < 4; ++i) {
            *(uint4*)&As[arow + i * 32][acol * 8] = va[i];
            *(uint4*)&Bs[arow + i * 32][acol * 8] = vb[i];
        }
        __syncthreads();
        if (kt < 31) {
#pragma unroll
            for (int i = 0; i < 4; ++i) { va[i] = ga[(size_t)i * 8192]; vb[i] = gb[(size_t)i * 8192]; }
            ga += 8; gb += 8;
        }
#pragma unroll
        for (int kk = 0; kk < 2; ++kk) {
            short8v af[4], bfr[4];
#pragma unroll
            for (int f = 0; f < 4; ++f) {
                af[f]  = *(const short8v*)&As[wr * 64 + f * 16 + l15][kk * 32 + l4 * 8];
                bfr[f] = *(const short8v*)&Bs[wc * 64 + f * 16 + l15][kk * 32 + l4 * 8];
            }
#pragma unroll
            for (int fm = 0; fm < 4; ++fm)
#pragma unroll
                for (int fn = 0; fn < 4; ++fn)
                    acc[fm][fn] = __builtin_amdgcn_mfma_f32_16x16x32_bf16(af[fm], bfr[fn], acc[fm][fn], 0, 0, 0);
        }
    }
    unsigned short* epi = (unsigned short*)(&As[0][0]) + (size_t)w * (16 * 72);
    int erow8 = lane >> 3;
    int ecol8 = lane & 7;
#pragma unroll
    for (int fm = 0; fm < 4; ++fm) {
        __syncthreads();
#pragma unroll
        for (int fn = 0; fn < 4; ++fn)
#pragma unroll
            for (int rr = 0; rr < 4; ++rr)
                epi[(l4 * 4 + rr) * 72 + fn * 16 + l15] = f2bf(acc[fm][fn][rr]);
        __syncthreads();
#pragma unroll
        for (int rh = 0; rh < 2; ++rh) {
            int lrow = rh * 8 + erow8;
            int grow = mb + wr * 64 + fm * 16 + lrow;
            if (grow < NN) {
                *(uint4*)(CH + (size_t)grow * THL + nb + wc * 64 + ecol8 * 8)
                    = *(const uint4*)&epi[lrow * 72 + ecol8 * 8];
            }
        }
    }
}

// ---------------- fusion as tiled GEMM: K=128 (X fp32 + XAgg bf16), 64 cols ----------------
__global__ __launch_bounds__(256) void k_fus2(const float* __restrict__ X,
                                              const unsigned short* __restrict__ XAH,
                                              const float* __restrict__ W,
                                              const float* __restrict__ b,
                                              float* __restrict__ OUT) {
    __shared__ float Wt[2 * HH][68];
    __shared__ float As[HH][68];
    int tid = threadIdx.x;
    size_t r0 = (size_t)blockIdx.x * 64;
    for (int i = tid; i < HH * 2 * HH; i += 256) { int o = i >> 7, k = i & 127; Wt[k][o] = W[i]; }
    int row = tid >> 2, kq = tid & 3;
    int tx = tid & 15, ty = tid >> 4;
    float acc[4][4] = {};
    __syncthreads();
    {
        const float4* src = (const float4*)(X + (r0 + row) * HH + kq * 16);
#pragma unroll
        for (int j = 0; j < 4; ++j) {
            float4 v = src[j];
            As[kq * 16 + j * 4 + 0][row] = v.x;
            As[kq * 16 + j * 4 + 1][row] = v.y;
            As[kq * 16 + j * 4 + 2][row] = v.z;
            As[kq * 16 + j * 4 + 3][row] = v.w;
        }
    }
    __syncthreads();
#pragma unroll
    for (int k = 0; k < HH; ++k) {
        float4 av = *(const float4*)&As[k][ty * 4];
        float4 wv = *(const float4*)&Wt[k][tx * 4];
        acc[0][0] += av.x * wv.x; acc[0][1] += av.x * wv.y; acc[0][2] += av.x * wv.z; acc[0][3] += av.x * wv.w;
        acc[1][0] += av.y * wv.x; acc[1][1] += av.y * wv.y; acc[1][2] += av.y * wv.z; acc[1][3] += av.y * wv.w;
        acc[2][0] += av.z * wv.x; acc[2][1] += av.z * wv.y; acc[2][2] += av.z * wv.z; acc[2][3] += av.z * wv.w;
        acc[3][0] += av.w * wv.x; acc[3][1] += av.w * wv.y; acc[3][2] += av.w * wv.z; acc[3][3] += av.w * wv.w;
    }
    __syncthreads();
    {
        const uint4* s = (const uint4*)(XAH + (r0 + row) * HH + kq * 16);
        uint4 u0 = s[0], u1 = s[1];
        unsigned short us[16];
        *(uint4*)us = u0; *(uint4*)(us + 8) = u1;
#pragma unroll
        for (int j = 0; j < 16; ++j)
            As[kq * 16 + j][row] = bf2f(us[j]);
    }
    __syncthreads();
#pragma unroll
    for (int k = 0; k < HH; ++k) {
        float4 av = *(const float4*)&As[k][ty * 4];
        float4 wv = *(const float4*)&Wt[HH + k][tx * 4];
        acc[0][0] += av.x * wv.x; acc[0][1] += av.x * wv.y; acc[0][2] += av.x * wv.z; acc[0][3] += av.x * wv.w;
        acc[1][0] += av.y * wv.x; acc[1][1] += av.y * wv.y; acc[1][2] += av.y * wv.z; acc[1][3] += av.y * wv.w;
        acc[2][0] += av.z * wv.x; acc[2][1] += av.z * wv.y; acc[2][2] += av.z * wv.z; acc[2][3] += av.z * wv.w;
        acc[3][0] += av.w * wv.x; acc[3][1] += av.w * wv.y; acc[3][2] += av.w * wv.z; acc[3][3] += av.w * wv.w;
    }
    float4 bv = *(const float4*)(b + tx * 4);
#pragma unroll
    for (int ii = 0; ii < 4; ++ii) {
        float4 o;
        o.x = fmaxf(acc[ii][0] + bv.x, 0.f);
        o.y = fmaxf(acc[ii][1] + bv.y, 0.f);
        o.z = fmaxf(acc[ii][2] + bv.z, 0.f);
        o.w = fmaxf(acc[ii][3] + bv.w, 0.f);
        *(float4*)(OUT + (r0 + ty * 4 + ii) * HH + tx * 4) = o;
    }
}

// ---------------- GCN xw as tiled GEMM: K=64, 64 cols, bf16 output ----------------
__global__ __launch_bounds__(256) void k_xw2(const float* __restrict__ IN,
                                             const float* __restrict__ W,
                                             unsigned short* __restrict__ OUT) {
    __shared__ float Wt[HH][68];
    __shared__ float As[HH][68];
    int tid = threadIdx.x;
    size_t r0 = (size_t)blockIdx.x * 64;
    for (int i = tid; i < HH * HH; i += 256) { int o = i >> 6, k = i & 63; Wt[k][o] = W[i]; }
    int row = tid >> 2, kq = tid & 3;
    {
        const float4* src = (const float4*)(IN + (r0 + row) * HH + kq * 16);
#pragma unroll
        for (int j = 0; j < 4; ++j) {
            float4 v = src[j];
            As[kq * 16 + j * 4 + 0][row] = v.x;
            As[kq * 16 + j * 4 + 1][row] = v.y;
            As[kq * 16 + j * 4 + 2][row] = v.z;
            As[kq * 16 + j * 4 + 3][row] = v.w;
        }
    }
    __syncthreads();
    int tx = tid & 15, ty = tid >> 4;
    float acc[4][4] = {};
#pragma unroll
    for (int k = 0; k < HH; ++k) {
        float4 av = *(const float4*)&As[k][ty * 4];
        float4 wv = *(const float4*)&Wt[k][tx * 4];
        acc[0][0] += av.x * wv.x; acc[0][1] += av.x * wv.y; acc[0][2] += av.x * wv.z; acc[0][3] += av.x * wv.w;
        acc[1][0] += av.y * wv.x; acc[1][1] += av.y * wv.y; acc[1][2] += av.y * wv.z; acc[1][3] += av.y * wv.w;
        acc[2][0] += av.z * wv.x; acc[2][1] += av.z * wv.y; acc[2][2] += av.z * wv.z; acc[2][3] += av.z * wv.w;
        acc[3][0] += av.w * wv.x; acc[3][1] += av.w * wv.y; acc[3][2] += av.w * wv.z; acc[3][3] += av.w * wv.w;
    }
#pragma unroll
    for (int ii = 0; ii < 4; ++ii) {
        unsigned int p0 = (unsigned int)f2bf(acc[ii][0]) | ((unsigned int)f2bf(acc[ii][1]) << 16);
        unsigned int p1 = (unsigned int)f2bf(acc[ii][2]) | ((unsigned int)f2bf(acc[ii][3]) << 16);
        uint2 pk; pk.x = p0; pk.y = p1;
        *(uint2*)(OUT + (r0 + ty * 4 + ii) * HH + tx * 4) = pk;
    }
}

// ---------------- GCN aggregate (CSR, bf16 in) + bias + BN + relu ----------------
__global__ __launch_bounds__(256) void k_agg(const unsigned short* __restrict__ XW,
                                             const int* __restrict__ off,
                                             const int* __restrict__ csr_src,
                                             const float* __restrict__ csr_nrm,
                                             const float* __restrict__ bias,
                                             const float* __restrict__ g,
                                             const float* __restrict__ bb,
                                             const float* __restrict__ m,
                                             const float* __restrict__ v,
                                             float* __restrict__ OUT) {
    int dst = blockIdx.x, ch = blockIdx.y, tid = threadIdx.x;
    int base = ch * 1024 + tid * 4;
    float4 acc = make_float4(0.f, 0.f, 0.f, 0.f);
    int beg = off[dst], end = off[dst + 1];
    for (int e = beg; e < end; ++e) {
        int src = csr_src[e];
        float w = csr_nrm[e];
        uint2 u = *(const uint2*)(XW + (size_t)src * THL + base);
        acc.x += w * bf2f((unsigned short)(u.x & 0xffff));
        acc.y += w * bf2f((unsigned short)(u.x >> 16));
        acc.z += w * bf2f((unsigned short)(u.y & 0xffff));
        acc.w += w * bf2f((unsigned short)(u.y >> 16));
    }
    int h0 = base & 63;
    float4 bs = *(const float4*)(bias + h0);
    float4 gv = *(const float4*)(g + h0);
    float4 vv = *(const float4*)(v + h0);
    float4 mv = *(const float4*)(m + h0);
    float4 bv = *(const float4*)(bb + h0);
    float4 o;
    o.x = fmaxf((acc.x + bs.x - mv.x) * rsqrtf(vv.x + EPSBN) * gv.x + bv.x, 0.f);
    o.y = fmaxf((acc.y + bs.y - mv.y) * rsqrtf(vv.y + EPSBN) * gv.y + bv.y, 0.f);
    o.z = fmaxf((acc.z + bs.z - mv.z) * rsqrtf(vv.z + EPSBN) * gv.z + bv.z, 0.f);
    o.w = fmaxf((acc.w + bs.w - mv.w) * rsqrtf(vv.w + EPSBN) * gv.w + bv.w, 0.f);
    *(float4*)(OUT + (size_t)dst * THL + base) = o;
}

// ---------------- MFMA 2-layer GRU: 16 nodes/block, 4 waves, weights as B-frags ----------------
// wave w owns output cols [16w,16w+16) of all 3 gates (N-tiles w, w+4, w+8).
// Verified C-layout (col=lane&15, row=(lane>>4)*4+reg) => r/z/n for the same
// (node, col) land in the same lane/reg across gate tiles: gate combine is pure
// register elementwise. h kept fp32 (combine) + bf16 (MFMA A-operand) in LDS.
__global__ __launch_bounds__(256, 1) void k_gruM(const float* __restrict__ IN,
                                                 const float* __restrict__ wih0, const float* __restrict__ whh0,
                                                 const float* __restrict__ bih0, const float* __restrict__ bhh0,
                                                 const float* __restrict__ wih1, const float* __restrict__ whh1,
                                                 const float* __restrict__ bih1, const float* __restrict__ bhh1,
                                                 float* __restrict__ hout) {
    __shared__ float hf0[NB][68];
    __shared__ float hf1[NB][68];
    __shared__ unsigned short hb0[NB][72];
    __shared__ unsigned short hb1[NB][72];
    int tid = threadIdx.x;
    int w = tid >> 6, lane = tid & 63;
    int l15 = lane & 15, l4 = lane >> 4;
    int nb0 = blockIdx.x * NB;
    // ---- B-frags: [mat][gate][kk], rows 64*g + 16*w + l15, k = kk*32 + l4*8 + e ----
    short8v bw[4][3][2];
    const float* Wm[4] = { wih0, whh0, wih1, whh1 };
#pragma unroll
    for (int m = 0; m < 4; ++m)
#pragma unroll
        for (int g = 0; g < 3; ++g)
#pragma unroll
            for (int kk = 0; kk < 2; ++kk) {
                const float* src = Wm[m] + (size_t)(64 * g + 16 * w + l15) * HH + kk * 32 + l4 * 8;
                float4 v0 = *(const float4*)src;
                float4 v1 = *(const float4*)(src + 4);
                short8v f;
                f[0] = (short)f2bf(v0.x); f[1] = (short)f2bf(v0.y);
                f[2] = (short)f2bf(v0.z); f[3] = (short)f2bf(v0.w);
                f[4] = (short)f2bf(v1.x); f[5] = (short)f2bf(v1.y);
                f[6] = (short)f2bf(v1.z); f[7] = (short)f2bf(v1.w);
                bw[m][g][kk] = f;
            }
    int jr = 16 * w + l15;   // this lane's output column in [0,64)
    float b0r = bih0[jr] + bhh0[jr];
    float b0z = bih0[64 + jr] + bhh0[64 + jr];
    float b0n = bih0[128 + jr];
    float h0n = bhh0[128 + jr];
    float b1r = bih1[jr] + bhh1[jr];
    float b1z = bih1[64 + jr] + bhh1[64 + jr];
    float b1n = bih1[128 + jr];
    float h1n = bhh1[128 + jr];
    for (int i = tid; i < NB * 68; i += 256) { ((float*)hf0)[i] = 0.f; ((float*)hf1)[i] = 0.f; }
    for (int i = tid; i < NB * 72; i += 256) { ((unsigned short*)hb0)[i] = 0; ((unsigned short*)hb1)[i] = 0; }
    __syncthreads();
    const float* xb = IN + (size_t)(nb0 + l15) * (TT * HH);
#pragma unroll 1
    for (int t = 0; t < TT; ++t) {
        // ---- build A-frags from old state (and x_t) ----
        short8v ax[2], ah0[2], ah1[2];
#pragma unroll
        for (int kk = 0; kk < 2; ++kk) {
            const float* xs = xb + t * HH + kk * 32 + l4 * 8;
            float4 v0 = *(const float4*)xs;
            float4 v1 = *(const float4*)(xs + 4);
            short8v f;
            f[0] = (short)f2bf(v0.x); f[1] = (short)f2bf(v0.y);
            f[2] = (short)f2bf(v0.z); f[3] = (short)f2bf(v0.w);
            f[4] = (short)f2bf(v1.x); f[5] = (short)f2bf(v1.y);
            f[6] = (short)f2bf(v1.z); f[7] = (short)f2bf(v1.w);
            ax[kk] = f;
            ah0[kk] = *(const short8v*)&hb0[l15][kk * 32 + l4 * 8];
            ah1[kk] = *(const short8v*)&hb1[l15][kk * 32 + l4 * 8];
        }
        __syncthreads();   // all waves captured old h state
        // ---- layer 0 ----
        {
            f32x4 gr = { b0r, b0r, b0r, b0r };
            f32x4 gz = { b0z, b0z, b0z, b0z };
            f32x4 gn = { b0n, b0n, b0n, b0n };
            f32x4 hr = { 0.f, 0.f, 0.f, 0.f };
            f32x4 hz = { 0.f, 0.f, 0.f, 0.f };
            f32x4 hn = { h0n, h0n, h0n, h0n };
#pragma unroll
            for (int kk = 0; kk < 2; ++kk) {
                gr = __builtin_amdgcn_mfma_f32_16x16x32_bf16(ax[kk], bw[0][0][kk], gr, 0, 0, 0);
                gz = __builtin_amdgcn_mfma_f32_16x16x32_bf16(ax[kk], bw[0][1][kk], gz, 0, 0, 0);
                gn = __builtin_amdgcn_mfma_f32_16x16x32_bf16(ax[kk], bw[0][2][kk], gn, 0, 0, 0);
                hr = __builtin_amdgcn_mfma_f32_16x16x32_bf16(ah0[kk], bw[1][0][kk], hr, 0, 0, 0);
                hz = __builtin_amdgcn_mfma_f32_16x16x32_bf16(ah0[kk], bw[1][1][kk], hz, 0, 0, 0);
                hn = __builtin_amdgcn_mfma_f32_16x16x32_bf16(ah0[kk], bw[1][2][kk], hn, 0, 0, 0);
            }
#pragma unroll
            for (int i = 0; i < 4; ++i) {
                int node = l4 * 4 + i;
                float r = fsigmoid(gr[i] + hr[i]);
                float z = fsigmoid(gz[i] + hz[i]);
                float nn2 = tanhf(gn[i] + r * hn[i]);
                float ho = hf0[node][jr];
                float hv = (1.f - z) * nn2 + z * ho;
                hf0[node][jr] = hv;
                hb0[node][jr] = f2bf(hv);
            }
        }
        __syncthreads();   // h0(t) visible
        // ---- layer 1 ----
        {
            short8v ah0n[2];
#pragma unroll
            for (int kk = 0; kk < 2; ++kk)
                ah0n[kk] = *(const short8v*)&hb0[l15][kk * 32 + l4 * 8];
            f32x4 gr = { b1r, b1r, b1r, b1r };
            f32x4 gz = { b1z, b1z, b1z, b1z };
            f32x4 gn = { b1n, b1n, b1n, b1n };
            f32x4 hr = { 0.f, 0.f, 0.f, 0.f };
            f32x4 hz = { 0.f, 0.f, 0.f, 0.f };
            f32x4 hn = { h1n, h1n, h1n, h1n };
#pragma unroll
            for (int kk = 0; kk < 2; ++kk) {
                gr = __builtin_amdgcn_mfma_f32_16x16x32_bf16(ah0n[kk], bw[2][0][kk], gr, 0, 0, 0);
                gz = __builtin_amdgcn_mfma_f32_16x16x32_bf16(ah0n[kk], bw[2][1][kk], gz, 0, 0, 0);
                gn = __builtin_amdgcn_mfma_f32_16x16x32_bf16(ah0n[kk], bw[2][2][kk], gn, 0, 0, 0);
                hr = __builtin_amdgcn_mfma_f32_16x16x32_bf16(ah1[kk], bw[3][0][kk], hr, 0, 0, 0);
                hz = __builtin_amdgcn_mfma_f32_16x16x32_bf16(ah1[kk], bw[3][1][kk], hz, 0, 0, 0);
                hn = __builtin_amdgcn_mfma_f32_16x16x32_bf16(ah1[kk], bw[3][2][kk], hn, 0, 0, 0);
            }
#pragma unroll
            for (int i = 0; i < 4; ++i) {
                int node = l4 * 4 + i;
                float r = fsigmoid(gr[i] + hr[i]);
                float z = fsigmoid(gz[i] + hz[i]);
                float nn2 = tanhf(gn[i] + r * hn[i]);
                float ho = hf1[node][jr];
                float hv = (1.f - z) * nn2 + z * ho;
                hf1[node][jr] = hv;
                hb1[node][jr] = f2bf(hv);
            }
        }
        __syncthreads();   // h1(t) visible before next step's frag builds
    }
    for (int i = tid; i < NB * HH; i += 256) {
        int node = i >> 6, j = i & 63;
        hout[(size_t)(nb0 + node) * HH + j] = hf1[node][j];
    }
}

// ---------------- head: BN + relu + linear + log_softmax ----------------
__global__ __launch_bounds__(256) void k_head(const float* __restrict__ Hf,
                                              const float* __restrict__ g, const float* __restrict__ b,
                                              const float* __restrict__ m, const float* __restrict__ v,
                                              const float* __restrict__ W, const float* __restrict__ wb,
                                              float* __restrict__ out) {
    __shared__ float hb[4][HH];
    __shared__ float lg[4][CC];
    int tid = threadIdx.x;
    int n0 = blockIdx.x * 4;
    int wv = tid >> 6, lane = tid & 63;
    int n = n0 + wv;
    float x = Hf[(size_t)n * HH + lane];
    x = (x - m[lane]) * rsqrtf(v[lane] + EPSBN) * g[lane] + b[lane];
    hb[wv][lane] = fmaxf(x, 0.f);
    __syncthreads();
    if (tid < 4 * CC) {
        int nn = tid / CC, c = tid % CC;
        float acc = wb[c];
        for (int f = 0; f < HH; ++f) acc += hb[nn][f] * W[c * HH + f];
        lg[nn][c] = acc;
    }
    __syncthreads();
    if (tid < 4 * CC) {
        int nn = tid / CC, c = tid % CC;
        float mx = -1e30f;
#pragma unroll
        for (int i = 0; i < CC; ++i) mx = fmaxf(mx, lg[nn][i]);
        float s = 0.f;
#pragma unroll
        for (int i = 0; i < CC; ++i) s += __expf(lg[nn][i] - mx);
        out[(size_t)(n0 + nn) * CC + c] = lg[nn][c] - mx - __logf(s);
    }
}

// ---------------- launch ----------------
extern "C" void kernel_launch(void* const* d_in, const int* in_sizes, int n_in,
                              void* d_out, int out_size, void* d_ws, size_t ws_size,
                              hipStream_t stream) {
    const float* x_seq     = (const float*)d_in[0];
    const int*   edge_idx  = (const int*)d_in[1];
    const float* edge_w    = (const float*)d_in[2];
    const float* causal_w  = (const float*)d_in[3];
    const float* lin_in_w  = (const float*)d_in[4];
    const float* lin_in_b  = (const float*)d_in[5];
    const float* fusion_w  = (const float*)d_in[6];
    const float* fusion_b  = (const float*)d_in[7];
    const float* gcn_w0    = (const float*)d_in[8];
    const float* gcn_b0    = (const float*)d_in[9];
    const float* gcn_w1    = (const float*)d_in[10];
    const float* gcn_b1    = (const float*)d_in[11];
    const float* bn0_g = (const float*)d_in[12], *bn0_b = (const float*)d_in[13];
    const float* bn0_m = (const float*)d_in[14], *bn0_v = (const float*)d_in[15];
    const float* bn1_g = (const float*)d_in[16], *bn1_b = (const float*)d_in[17];
    const float* bn1_m = (const float*)d_in[18], *bn1_v = (const float*)d_in[19];
    const float* wih0 = (const float*)d_in[20], *whh0 = (const float*)d_in[21];
    const float* bih0 = (const float*)d_in[22], *bhh0 = (const float*)d_in[23];
    const float* wih1 = (const float*)d_in[24], *whh1 = (const float*)d_in[25];
    const float* bih1 = (const float*)d_in[26], *bhh1 = (const float*)d_in[27];
    const float* bno_g = (const float*)d_in[28], *bno_b = (const float*)d_in[29];
    const float* bno_m = (const float*)d_in[30], *bno_v = (const float*)d_in[31];
    const float* lout_w = (const float*)d_in[32], *lout_b = (const float*)d_in[33];
    float* out = (float*)d_out;

    float* wsf = (float*)d_ws;
    unsigned short* WCH = (unsigned short*)(wsf + OFF_WC);
    float* XA  = wsf + OFF_XA;
    float* XB  = wsf + OFF_XB;
    float* XC  = wsf + OFF_XC;
    unsigned short* XAT = (unsigned short*)(wsf + OFF_XC);
    unsigned short* XBH = (unsigned short*)(wsf + OFF_XB);   // bf16: x_agg (gemm C), then xw output
    float* DEG = wsf + OFF_DEG;
    int* CNT   = (int*)(wsf + OFF_CNT);
    int* CUR   = (int*)(wsf + OFF_CUR);
    int* OFFP  = (int*)(wsf + OFF_OFF);
    int* CSRS  = (int*)(wsf + OFF_CSRS);
    float* CSRN = wsf + OFF_CSRN;
    float* HST  = wsf + OFF_HST;

    // CSR + degree build
    k_zero<<<8, 256, 0, stream>>>(CNT, CUR, DEG);
    k_count<<<(ETOT + 255) / 256, 256, 0, stream>>>(edge_idx, edge_w, CNT, DEG);
    k_scan<<<1, 1024, 0, stream>>>(CNT, OFFP);
    k_fill<<<(ETOT + 255) / 256, 256, 0, stream>>>(edge_idx, edge_w, DEG, OFFP, CUR, CSRS, CSRN);

    hipMemsetAsync(WCH, 0, (size_t)2048 * 2048 * 2, stream);
    k_softmax<<<NN, 256, 0, stream>>>(causal_w, WCH);
    // lin_in -> XA [N,T,H] fp32
    k_lin2<<<NN, 256, 0, stream>>>(x_seq, lin_in_w, lin_in_b, XA);
    // transpose+cast: XA -> XAh_t bf16 [4096][2048]
    dim3 tg(THL / 64, 2048 / 64);
    k_tr<<<tg, 256, 0, stream>>>(XA, XAT);
    // x_agg = WCh @ X (MFMA bf16) -> XBH (bf16)
    dim3 gg(THL / 128, 2048 / 128);
    k_gemm_bf<<<gg, 256, 0, stream>>>(WCH, XAT, XBH);
    // fusion -> XC  (X fp32 + XAgg bf16)
    k_fus2<<<NN, 256, 0, stream>>>(XA, XBH, fusion_w, fusion_b, XC);
    // GCN layer 0: XC -> XBH (xw, bf16) -> XA (agg+bn+relu, fp32)
    k_xw2<<<NN, 256, 0, stream>>>(XC, gcn_w0, XBH);
    dim3 ag(NN, 4);
    k_agg<<<ag, 256, 0, stream>>>(XBH, OFFP, CSRS, CSRN, gcn_b0, bn0_g, bn0_b, bn0_m, bn0_v, XA);
    // GCN layer 1: XA -> XBH -> XC
    k_xw2<<<NN, 256, 0, stream>>>(XA, gcn_w1, XBH);
    k_agg<<<ag, 256, 0, stream>>>(XBH, OFFP, CSRS, CSRN, gcn_b1, bn1_g, bn1_b, bn1_m, bn1_v, XC);

    // MFMA 2-layer GRU: XC -> final h in HST (single dispatch, 125 blocks)
    k_gruM<<<NN / NB, 256, 0, stream>>>(XC, wih0, whh0, bih0, bhh0,
                                        wih1, whh1, bih1, bhh1, HST);

    // head
    k_head<<<NN / 4, 256, 0, stream>>>(HST, bno_g, bno_b, bno_m, bno_v, lout_w, lout_b, out);
}